// Round 3
// baseline (5257.178 us; speedup 1.0000x reference)
//
#include <hip/hip_runtime.h>
#include <hip/hip_bf16.h>
#include <math.h>

// Problem constants
#define NTOK  65536      // B*T
#define CDIM  512
#define NHEAD 8
#define HSZ   64
#define NLAYER 6
#define DFF   2048
#define VOCAB 65

typedef unsigned short u16;
typedef __attribute__((ext_vector_type(8))) __bf16 bf16x8;
typedef __attribute__((ext_vector_type(4))) float f32x4;
typedef __attribute__((ext_vector_type(8))) unsigned short ushort8;

__device__ __forceinline__ float b2f(u16 u) {
    union { unsigned int i; float f; } x; x.i = ((unsigned int)u) << 16; return x.f;
}
__device__ __forceinline__ u16 f2b(float f) {
    union { float f; unsigned int i; } x; x.f = f;
    unsigned int r = x.i + 0x7fffu + ((x.i >> 16) & 1u);   // RNE
    return (u16)(r >> 16);
}

__device__ __forceinline__ void async16(const u16* g, u16* l) {
    __builtin_amdgcn_global_load_lds(
        (const __attribute__((address_space(1))) void*)g,
        (__attribute__((address_space(3))) void*)l, 16, 0, 0);
}

// ---------------------------------------------------------------------------
// R10: 256x256 persistent GEMM, COMPILER-SCHEDULED inner loop.
//   C[M x N] = A[M x K] @ Bt[N x K]^T  (bf16 in, fp32 MFMA accum)
// R1/R2 post-mortem: three schedules (2-barrier, 8-phase, persistent 8-phase)
// all land at 27-28% MfmaUtil / 7575 cyc per block-K-step vs 2483 MFMA floor.
// m201 pays 3300 cyc for the same K-step on the same HW -> our overhead is in
// EMITTED CODE: (1) sched_barrier(0) walls x4/K-step (rule 18 doesn't apply —
// our ds_reads are compiler-generated, deps force correct waits anyway),
// (2) lgkmcnt(0) full drains where the compiler would emit counted waits,
// (3) runtime K/lda/N/tpb -> address VALU + branches (VALUBusy 24%).
// Fix: all-compile-time template; ONE barrier + ONE vmcnt(0) per K-step:
//   slot t top: stage A,B of slot t+1 -> buffer c^1 (dead all of slot t)
//   then 24 ds_read + 64 MFMA in plain HIP (compiler inserts counted lgkm,
//   interleaves VALU/reads/MFMA freely; setprio around MFMA clusters)
//   slot t end: vmcnt(0) — cheap: stages were issued a full slot earlier —
//   then s_barrier.
// Cross-wave ledger: each wave drains its own stages (vmcnt 0) before the
// barrier -> after barrier, buffer c^1 fully valid for ALL waves. Reads of
// buffer c are consumed by MFMAs that precede the barrier -> slot t+1's
// stages into c can't race them. One barrier suffices.
// Persistence: block owns m-stripe, sweeps TPB n-tiles; stage crosses tile
// boundary (A restage = same panel, L2-hot; B advances BSTRIDE). Parity:
// every tile starts at c=0 (NK even). K order per tile unchanged vs R7-R9
// -> bitwise-identical output.
// T2 swizzle both-sides (rule 21): linear LDS dest + global src granule
// (tid&7)^(srow&7); read granule (kk*4+quad)^(r16&7). Bank conflicts = 0
// (verified R1/R2).
// ---------------------------------------------------------------------------
template<int JB, int IB>
__device__ __forceinline__ void mfma_quad(f32x4 (&acc)[4][8],
                                          const bf16x8 (&af)[4][2],
                                          const bf16x8 (&bf)[4][2])
{
#pragma unroll
    for (int kk = 0; kk < 2; kk++)
#pragma unroll
        for (int j = 0; j < 2; j++)
#pragma unroll
            for (int i = 0; i < 4; i++)
                acc[JB + j][IB + i] = __builtin_amdgcn_mfma_f32_16x16x32_bf16(
                    bf[JB + j][kk], af[i][kk], acc[JB + j][IB + i], 0, 0, 0);
}

template<int EPI, int K, int LDA, int N, int TPB>
__global__ __launch_bounds__(512, 2)
void gemm256(const u16* __restrict__ A, const u16* __restrict__ Bt,
             void* Cout, const float* __restrict__ bias, const u16* res)
{
    extern __shared__ __attribute__((aligned(16))) u16 lds[];
    constexpr int NK = K >> 6;                    // K-steps per tile (even)
    constexpr size_t BSTRIDE = (size_t)256 * K;   // per n-tile B stride
    const int tid = threadIdx.x;
    const int bid = blockIdx.x;

    // persistent mapping: XCD owns a contiguous stripe band
    const int per_x = gridDim.x >> 4;            // nstripe/8
    const int xcd = bid & 7, wblk = bid >> 3;
    const int mt = xcd * per_x + (wblk >> 1);
    const int q  = wblk & 1;
    const int m0 = mt * 256;
    const int nt0 = q * TPB;

    const int lane = tid & 63, wvv = tid >> 6;   // 8 waves
    const int wvm = wvv >> 2, wvn = wvv & 3;     // 2M x 4N
    const int r16 = lane & 15, quad = lane >> 4;
    const int gk0 = quad ^ (r16 & 7);            // swizzled granule (kk=0)
    const int g0x8 = gk0 * 8, g1x8 = (gk0 ^ 4) * 8;
    const int arow = wvm * 128 + r16;
    const int brow = wvn * 64 + r16;

    // staging: thread -> (row = srow + 64*sub (+128*h), granule sg)
    const int srow = tid >> 3;                   // 0..63
    const int sg = (tid & 7) ^ (srow & 7);       // inverse-swizzled global granule
    const u16* pA  = A  + (size_t)(m0 + srow) * LDA + sg * 8;
    const u16* pB0 = Bt + (size_t)(nt0 * 256 + srow) * K + sg * 8;
    u16* const ldst = lds + tid * 8;
    constexpr size_t ldaq = (size_t)64 * LDA, ldah = (size_t)128 * LDA;
    constexpr size_t kq = (size_t)64 * K, kh = (size_t)128 * K;

    f32x4 acc[4][8];
    bf16x8 af[4][2], bf[4][2];

#define STAGE_A(c, kt, h) do { \
    async16(pA + ((h) ? ldah : 0) + (size_t)((kt) * 64),        ldst + (c) * 32768 + (h) * 8192); \
    async16(pA + ((h) ? ldah : 0) + ldaq + (size_t)((kt) * 64), ldst + (c) * 32768 + (h) * 8192 + 4096); } while (0)
#define STAGE_B(c, pb, kt, h) do { \
    async16((pb) + ((h) ? kh : 0) + (size_t)((kt) * 64),        ldst + (c) * 32768 + 16384 + (h) * 8192); \
    async16((pb) + ((h) ? kh : 0) + kq + (size_t)((kt) * 64),   ldst + (c) * 32768 + 16384 + (h) * 8192 + 4096); } while (0)
#define LD_A4(IB0) do { _Pragma("unroll") \
    for (int i = 0; i < 4; i++) { \
        const int ro = cb + (arow + ((IB0) + i) * 16) * 64; \
        af[i][0] = *(const bf16x8*)(const void*)&lds[ro + g0x8]; \
        af[i][1] = *(const bf16x8*)(const void*)&lds[ro + g1x8]; \
    } } while (0)
#define LD_B2(JB0) do { _Pragma("unroll") \
    for (int j = 0; j < 2; j++) { \
        const int ro = cb + 16384 + (brow + ((JB0) + j) * 16) * 64; \
        bf[(JB0) + j][0] = *(const bf16x8*)(const void*)&lds[ro + g0x8]; \
        bf[(JB0) + j][1] = *(const bf16x8*)(const void*)&lds[ro + g1x8]; \
    } } while (0)

    // prologue: stage slot (j=0, t=0) -> buffer 0, drain, barrier
    STAGE_A(0, 0, 0); STAGE_A(0, 0, 1);
    STAGE_B(0, pB0, 0, 0); STAGE_B(0, pB0, 0, 1);
    asm volatile("s_waitcnt vmcnt(0)" ::: "memory");
    __builtin_amdgcn_s_barrier();

    for (int j = 0; j < TPB; ++j) {
        const u16* pBj = pB0 + (size_t)j * BSTRIDE;
#pragma unroll
        for (int jj = 0; jj < 4; jj++)
#pragma unroll
            for (int ii = 0; ii < 8; ii++)
                acc[jj][ii] = (f32x4){0.f, 0.f, 0.f, 0.f};

#pragma unroll 4
        for (int t = 0; t < NK; ++t) {
            const int c = t & 1;
            const int cb = c * 32768;
            // ---- stage next slot into c^1 (dead buffer) ----
            if (t + 1 < NK) {
                STAGE_A(c ^ 1, t + 1, 0); STAGE_A(c ^ 1, t + 1, 1);
                STAGE_B(c ^ 1, pBj, t + 1, 0); STAGE_B(c ^ 1, pBj, t + 1, 1);
            } else if (j + 1 < TPB) {
                STAGE_A(c ^ 1, 0, 0); STAGE_A(c ^ 1, 0, 1);
                STAGE_B(c ^ 1, pBj + BSTRIDE, 0, 0); STAGE_B(c ^ 1, pBj + BSTRIDE, 0, 1);
            }
            // ---- fragments + MFMA, compiler-scheduled (counted lgkm) ----
            LD_A4(0); LD_B2(0); LD_B2(2);
            __builtin_amdgcn_s_setprio(1);
            mfma_quad<0, 0>(acc, af, bf);
            mfma_quad<2, 0>(acc, af, bf);
            __builtin_amdgcn_s_setprio(0);
            LD_A4(4);
            __builtin_amdgcn_s_setprio(1);
            mfma_quad<0, 4>(acc, af, bf);
            mfma_quad<2, 4>(acc, af, bf);
            __builtin_amdgcn_s_setprio(0);
            // ---- slot end: drain own stages (issued a full slot ago), align
            asm volatile("s_waitcnt vmcnt(0)" ::: "memory");
            __builtin_amdgcn_s_barrier();
        }

        // epilogue for tile (mt, nt0+j) — after barrier, overlaps next tile
        const int n0 = (nt0 + j) * 256;
#pragma unroll
        for (int i = 0; i < 8; i++) {
            const int row = m0 + wvm * 128 + i * 16 + r16;
#pragma unroll
            for (int jc = 0; jc < 4; jc++) {
                const int colb = n0 + wvn * 64 + jc * 16 + quad * 4;
                float v[4];
#pragma unroll
                for (int r = 0; r < 4; r++) v[r] = acc[jc][i][r];
                if (EPI == 1 || EPI == 2) {
                    const f32x4 b4 = *(const f32x4*)(const void*)&bias[colb];
#pragma unroll
                    for (int r = 0; r < 4; r++) v[r] += b4[r];
                }
                if (EPI == 1) {
                    const uint2 rv = *(const uint2*)(const void*)&res[(size_t)row * N + colb];
                    v[0] += b2f((u16)(rv.x & 0xffffu));
                    v[1] += b2f((u16)(rv.x >> 16));
                    v[2] += b2f((u16)(rv.y & 0xffffu));
                    v[3] += b2f((u16)(rv.y >> 16));
                }
                if (EPI == 2) {
#pragma unroll
                    for (int r = 0; r < 4; r++) v[r] = fmaxf(v[r], 0.f);
                }
                uint2 o;
                o.x = (unsigned)f2b(v[0]) | ((unsigned)f2b(v[1]) << 16);
                o.y = (unsigned)f2b(v[2]) | ((unsigned)f2b(v[3]) << 16);
                *(uint2*)(void*)&((u16*)Cout)[(size_t)row * N + colb] = o;
            }
        }
    }
#undef STAGE_A
#undef STAGE_B
#undef LD_A4
#undef LD_B2
}

// ---------------------------------------------------------------------------
// Legacy 256x128 GEMM — kept ONLY for the LM head (N=128 doesn't tile to 256).
// EPI 3: +bias -> f32, masked col < Nout.
// ---------------------------------------------------------------------------
template<int EPI>
__global__ __launch_bounds__(512)
void gemm_bt(const u16* __restrict__ A, const u16* __restrict__ Bt,
             void* __restrict__ Cout, const float* __restrict__ bias,
             const u16* __restrict__ res, int K, int lda, int N, int Nout)
{
    __shared__ u16 lA[2 * 256 * 32];
    __shared__ u16 lB[2 * 128 * 32];
    const int tid  = threadIdx.x;

    const int Nx = gridDim.x;
    const int id = blockIdx.y * Nx + blockIdx.x;
    const int xcd = id & 7;
    const int j0  = id >> 3;
    const int mt  = xcd + 8 * (j0 / Nx);
    const int nt  = j0 - (j0 / Nx) * Nx;
    const int m0  = mt * 256;
    const int n0  = nt * 128;

    const int lane = tid & 63;
    const int wv   = tid >> 6;
    const int wr   = (wv >> 1) * 64;
    const int wc   = (wv & 1) * 64;
    const int r16  = lane & 15;
    const int quad = lane >> 4;

    f32x4 acc[4][4] = {};

    const int srow = tid >> 2, skseg = (tid & 3) * 8;
    const u16* pA  = A  + (size_t)(m0 + srow) * lda + skseg;
    const u16* pA2 = pA + (size_t)128 * lda;
    const u16* pB  = Bt + (size_t)(n0 + srow) * K + skseg;
    u16* lAt = &lA[(size_t)tid * 8];
    u16* lBt = &lB[(size_t)tid * 8];

    for (int k0 = 0; k0 < K; k0 += 64) {
        async16(pA  + k0,      lAt);
        async16(pA2 + k0,      lAt + 4096);
        async16(pA  + k0 + 32, lAt + 8192);
        async16(pA2 + k0 + 32, lAt + 12288);
        async16(pB  + k0,      lBt);
        async16(pB  + k0 + 32, lBt + 4096);
        __syncthreads();

#pragma unroll
        for (int s = 0; s < 2; s++) {
            const u16* bA = &lA[s * 8192];
            const u16* bB = &lB[s * 4096];
            bf16x8 af[4], bfr[4];
#pragma unroll
            for (int i = 0; i < 4; i++)
                af[i] = *(const bf16x8*)(const void*)&bA[(wr + i * 16 + r16) * 32 + quad * 8];
#pragma unroll
            for (int j = 0; j < 4; j++)
                bfr[j] = *(const bf16x8*)(const void*)&bB[(wc + j * 16 + r16) * 32 + quad * 8];
#pragma unroll
            for (int j = 0; j < 4; j++)
#pragma unroll
                for (int i = 0; i < 4; i++)
                    acc[j][i] = __builtin_amdgcn_mfma_f32_16x16x32_bf16(bfr[j], af[i], acc[j][i], 0, 0, 0);
        }
        __syncthreads();
    }

#pragma unroll
    for (int i = 0; i < 4; i++) {
        const int row = m0 + wr + i * 16 + r16;
#pragma unroll
        for (int j = 0; j < 4; j++) {
            const int colb = n0 + wc + j * 16 + quad * 4;
            float v[4];
#pragma unroll
            for (int r = 0; r < 4; r++) v[r] = acc[j][i][r];
            if (EPI == 3) {
#pragma unroll
                for (int r = 0; r < 4; r++) {
                    const int col = colb + r;
                    if (col < Nout)
                        ((float*)Cout)[(size_t)row * Nout + col] = v[r] + bias[col];
                }
            } else {
                uint2 o;
                o.x = (unsigned)f2b(v[0]) | ((unsigned)f2b(v[1]) << 16);
                o.y = (unsigned)f2b(v[2]) | ((unsigned)f2b(v[3]) << 16);
                *(uint2*)(void*)&((u16*)Cout)[(size_t)row * N + colb] = o;
            }
        }
    }
}

// ---------------------------------------------------------------------------
// Attention: one wave per (b,h). T=8, HS=64. qkv layout [token][q|k|v, h*64+d].
// IN-PLACE into q-slot. NOTE: reference scale = C^-0.5 = 512^-0.5.
// ---------------------------------------------------------------------------
__global__ __launch_bounds__(256)
void attn_k(u16* __restrict__ qkv)
{
    __shared__ float sq[4][8][65], sk[4][8][65], sv[4][8][65], sp[4][64];
    const int w = threadIdx.x >> 6, lane = threadIdx.x & 63;
    const int unit = blockIdx.x * 4 + w;
    const int b = unit >> 3, h = unit & 7;
    const size_t base = (size_t)b * 8 * 1536 + h * 64;
    {
        const int t = lane >> 3, d0 = (lane & 7) * 8;
        const ushort8 q8 = *(const ushort8*)(const void*)&qkv[base + t * 1536 + d0];
        const ushort8 k8 = *(const ushort8*)(const void*)&qkv[base + t * 1536 + 512 + d0];
        const ushort8 v8 = *(const ushort8*)(const void*)&qkv[base + t * 1536 + 1024 + d0];
#pragma unroll
        for (int i = 0; i < 8; i++) {
            sq[w][t][d0 + i] = b2f(q8[i]);
            sk[w][t][d0 + i] = b2f(k8[i]);
            sv[w][t][d0 + i] = b2f(v8[i]);
        }
    }
    __syncthreads();
    const int t = lane >> 3, s = lane & 7;
    float sc = -1e30f;
    if (s <= t) {
        float d = 0.f;
#pragma unroll
        for (int c = 0; c < 64; c++) d += sq[w][t][c] * sk[w][s][c];
        sc = d * 0.04419417382415922f;          // 512^-0.5
    }
    float mx = sc;
#pragma unroll
    for (int m = 1; m < 8; m <<= 1) mx = fmaxf(mx, __shfl_xor(mx, m, 8));
    float e = __expf(sc - mx);
    if (s > t) e = 0.f;
    float sum = e;
#pragma unroll
    for (int m = 1; m < 8; m <<= 1) sum += __shfl_xor(sum, m, 8);
    sp[w][lane] = e / sum;
    __syncthreads();
    {
        const int tt = lane >> 3, d0 = (lane & 7) * 8;
        float a[8] = {};
#pragma unroll
        for (int ss = 0; ss < 8; ss++) {
            const float p = sp[w][tt * 8 + ss];
#pragma unroll
            for (int i = 0; i < 8; i++) a[i] += p * sv[w][ss][d0 + i];
        }
        ushort8 o;
#pragma unroll
        for (int i = 0; i < 8; i++) o[i] = f2b(a[i]);
        *(ushort8*)(void*)&qkv[base + tt * 1536 + d0] = o;
    }
}

// ---------------------------------------------------------------------------
// LayerNorm: wave per token, 8 elems/lane, shuffle reduction. In-place OK.
// ---------------------------------------------------------------------------
__global__ __launch_bounds__(256)
void ln_k(const u16* __restrict__ y, const float* __restrict__ g,
          const float* __restrict__ be, u16* __restrict__ x)
{
    const int w = threadIdx.x >> 6, lane = threadIdx.x & 63;
    const size_t tok = (size_t)blockIdx.x * 4 + w;
    const u16* row = y + tok * 512 + lane * 8;
    ushort8 raw = *(const ushort8*)(const void*)row;
    float v[8];
#pragma unroll
    for (int i = 0; i < 8; i++) v[i] = b2f(raw[i]);
    float s = 0.f;
#pragma unroll
    for (int i = 0; i < 8; i++) s += v[i];
#pragma unroll
    for (int m = 1; m < 64; m <<= 1) s += __shfl_xor(s, m, 64);
    const float mu = s * (1.f / 512.f);
    float q = 0.f;
#pragma unroll
    for (int i = 0; i < 8; i++) { float d = v[i] - mu; q += d * d; }
#pragma unroll
    for (int m = 1; m < 64; m <<= 1) q += __shfl_xor(q, m, 64);
    const float inv = rsqrtf(q * (1.f / 512.f) + 1e-5f);
    f32x4 g0  = *(const f32x4*)(const void*)&g[lane * 8];
    f32x4 g1  = *(const f32x4*)(const void*)&g[lane * 8 + 4];
    f32x4 b0  = *(const f32x4*)(const void*)&be[lane * 8];
    f32x4 b1v = *(const f32x4*)(const void*)&be[lane * 8 + 4];
    ushort8 o;
#pragma unroll
    for (int i = 0; i < 4; i++) o[i]     = f2b((v[i] - mu) * inv * g0[i] + b0[i]);
#pragma unroll
    for (int i = 0; i < 4; i++) o[i + 4] = f2b((v[i + 4] - mu) * inv * g1[i] + b1v[i]);
    *(ushort8*)(void*)&x[tok * 512 + lane * 8] = o;
}

// ---------------------------------------------------------------------------
// Embedding: vectorized. thread -> (token, 8-col segment).
// ---------------------------------------------------------------------------
__global__ __launch_bounds__(256)
void embed_k(const int* __restrict__ idx, const float* __restrict__ tokt,
             const float* __restrict__ pos, u16* __restrict__ xb)
{
    const int gid = blockIdx.x * 256 + threadIdx.x;
    const int tk = gid >> 6, seg = (gid & 63) * 8;
    const int t = tk & 7;
    const int ix = idx[tk];
    const f32x4 a0 = *(const f32x4*)(const void*)&tokt[(size_t)ix * 512 + seg];
    const f32x4 a1 = *(const f32x4*)(const void*)&tokt[(size_t)ix * 512 + seg + 4];
    const f32x4 p0 = *(const f32x4*)(const void*)&pos[t * 512 + seg];
    const f32x4 p1 = *(const f32x4*)(const void*)&pos[t * 512 + seg + 4];
    ushort8 o;
#pragma unroll
    for (int i = 0; i < 4; i++) o[i]     = f2b(a0[i] + p0[i]);
#pragma unroll
    for (int i = 0; i < 4; i++) o[i + 4] = f2b(a1[i] + p1[i]);
    *(ushort8*)(void*)&xb[(size_t)tk * 512 + seg] = o;
}

// ---------------------------------------------------------------------------
// Weight converts (fp32 -> bf16 B^T layouts), LDS-tiled transposes
// ---------------------------------------------------------------------------
__global__ __launch_bounds__(256)
void conv_t2_k(const float* __restrict__ in, u16* __restrict__ out, int K, int N)
{
    __shared__ float t[32][33];
    const int tx = threadIdx.x & 31, ty4 = (threadIdx.x >> 5) * 4;
    const int n0 = blockIdx.x * 32, k0 = blockIdx.y * 32, l = blockIdx.z;
    const size_t per = (size_t)K * N;
    const float* src = in + l * per;
#pragma unroll
    for (int r = 0; r < 4; r++)
        t[ty4 + r][tx] = src[(size_t)(k0 + ty4 + r) * N + n0 + tx];
    __syncthreads();
    u16* dst = out + l * per;
#pragma unroll
    for (int r = 0; r < 4; r++)
        dst[(size_t)(n0 + ty4 + r) * K + k0 + tx] = f2b(t[tx][ty4 + r]);
}

__global__ __launch_bounds__(256)
void conv_qkv2_k(const float* __restrict__ wq, const float* __restrict__ wk,
                 const float* __restrict__ wv, u16* __restrict__ out)
{
    __shared__ float t[32][33];
    const int tx = threadIdx.x & 31, ty4 = (threadIdx.x >> 5) * 4;
    const int c0 = blockIdx.x * 32, d0 = blockIdx.y * 32;
    const int z = blockIdx.z;
    const int sel = z / 48, rem = z - sel * 48;
    const int l = rem >> 3, h = rem & 7;
    const float* src = (sel == 0) ? wq : (sel == 1) ? wk : wv;
    const float* sb = src + (((size_t)l * 8 + h) * 512) * 64;
#pragma unroll
    for (int r = 0; r < 4; r++)
        t[ty4 + r][tx] = sb[(size_t)(c0 + ty4 + r) * 64 + d0 + tx];
    __syncthreads();
    u16* dst = out + (size_t)l * 786432 + (size_t)(sel * 512 + h * 64 + d0) * 512;
#pragma unroll
    for (int r = 0; r < 4; r++)
        dst[(size_t)(ty4 + r) * 512 + c0 + tx] = f2b(t[tx][ty4 + r]);
}

__global__ __launch_bounds__(256)
void conv_lm_k(const float* __restrict__ lm_w, u16* __restrict__ out)
{
    int gid = blockIdx.x * 256 + threadIdx.x;
    int n = gid >> 9, c = gid & 511;
    out[gid] = (n < VOCAB) ? f2b(lm_w[(size_t)c * VOCAB + n]) : (u16)0;
}

// ---------------------------------------------------------------------------
extern "C" void kernel_launch(void* const* d_in, const int* in_sizes, int n_in,
                              void* d_out, int out_size, void* d_ws, size_t ws_size,
                              hipStream_t stream)
{
    const int*   idx    = (const int*)  d_in[0];
    const float* tokt   = (const float*)d_in[1];
    const float* post   = (const float*)d_in[2];
    const float* wq     = (const float*)d_in[3];
    const float* wk     = (const float*)d_in[4];
    const float* wvp    = (const float*)d_in[5];
    const float* proj_w = (const float*)d_in[6];
    const float* proj_b = (const float*)d_in[7];
    const float* w1     = (const float*)d_in[8];
    const float* b1     = (const float*)d_in[9];
    const float* w2     = (const float*)d_in[10];
    const float* b2     = (const float*)d_in[11];
    const float* ln1_g  = (const float*)d_in[12];
    const float* ln1_b  = (const float*)d_in[13];
    const float* ln2_g  = (const float*)d_in[14];
    const float* ln2_b  = (const float*)d_in[15];
    const float* lm_w   = (const float*)d_in[16];
    const float* lm_b   = (const float*)d_in[17];
    float* out = (float*)d_out;

    // 128 KiB dynamic LDS opt-in for the persistent GEMM (once per process).
    static int smem_set = 0;
    if (!smem_set) {
        smem_set = 1;
        hipFuncSetAttribute(reinterpret_cast<const void*>(&gemm256<0, 512, 512, 1536, 3>),
                            hipFuncAttributeMaxDynamicSharedMemorySize, 131072);
        hipFuncSetAttribute(reinterpret_cast<const void*>(&gemm256<1, 512, 1536, 512, 1>),
                            hipFuncAttributeMaxDynamicSharedMemorySize, 131072);
        hipFuncSetAttribute(reinterpret_cast<const void*>(&gemm256<2, 512, 512, 2048, 4>),
                            hipFuncAttributeMaxDynamicSharedMemorySize, 131072);
        hipFuncSetAttribute(reinterpret_cast<const void*>(&gemm256<1, 2048, 2048, 512, 1>),
                            hipFuncAttributeMaxDynamicSharedMemorySize, 131072);
    }

    char* ws = (char*)d_ws;
    u16* wqkvt = (u16*)(ws + 0);                     //  9,437,184
    u16* wprjt = (u16*)(ws + 9437184);               //  3,145,728
    u16* ww1t  = (u16*)(ws + 12582912);              // 12,582,912
    u16* ww2t  = (u16*)(ws + 25165824);              // 12,582,912
    u16* wlmt  = (u16*)(ws + 37748736);              //    131,072
    u16* xb    = (u16*)(ws + 37879808);              // 67,108,864  residual
    char* big  = ws + 104988672;                     // transient

    const size_t fixed_bytes = 104988672ull;
    const size_t avail = (ws_size > fixed_bytes) ? (ws_size - fixed_bytes) : 0;
    int chunk_a = 8192, chunk_m = 8192;
    const int cands[3] = {65536, 32768, 16384};
    for (int i = 0; i < 3; i++)
        if ((size_t)cands[i] * 3072ull <= avail) { chunk_a = cands[i]; break; }
    for (int i = 0; i < 3; i++)
        if ((size_t)cands[i] * 4096ull <= avail) { chunk_m = cands[i]; break; }
    const int nca = NTOK / chunk_a, ncm = NTOK / chunk_m;
    u16* qkvc = (u16*)big;                           // chunk_a x 1536
    u16* h1c  = (u16*)big;                           // chunk_m x 2048

    conv_qkv2_k<<<dim3(16, 2, 144), 256, 0, stream>>>(wq, wk, wvp, wqkvt);
    conv_t2_k  <<<dim3(16, 16, 6), 256, 0, stream>>>(proj_w, wprjt, 512, 512);
    conv_t2_k  <<<dim3(64, 16, 6), 256, 0, stream>>>(w1, ww1t, 512, 2048);
    conv_t2_k  <<<dim3(16, 64, 6), 256, 0, stream>>>(w2, ww2t, 2048, 512);
    conv_lm_k  <<<128 * 512 / 256, 256, 0, stream>>>(lm_w, wlmt);

    embed_k<<<NTOK * 64 / 256, 256, 0, stream>>>(idx, tokt, post, xb);

    for (int l = 0; l < NLAYER; l++) {
        // ---- attention phase ----
        for (int c = 0; c < nca; c++) {
            const size_t t0 = (size_t)c * chunk_a;
            const int grid = (chunk_a / 256) * 2;      // persistent: 2 blocks/stripe
            // qkv = x @ Wqkv   (tpb = 1536/256/2 = 3)
            gemm256<0, 512, 512, 1536, 3><<<dim3(grid), 512, 131072, stream>>>(
                xb + t0 * 512, wqkvt + (size_t)l * 786432, qkvc, nullptr, nullptr);
            // attention, in-place into q-slot of qkvc
            attn_k<<<chunk_a / 4, 256, 0, stream>>>(qkvc);
            // x = attno @ proj_w + proj_b + x   (A = q-slot, lda=1536; tpb=1)
            gemm256<1, 512, 1536, 512, 1><<<dim3(grid), 512, 131072, stream>>>(
                qkvc, wprjt + (size_t)l * 262144, xb + t0 * 512,
                proj_b + l * 512, xb + t0 * 512);
        }
        // x = LN1(x)  (in-place)
        ln_k<<<NTOK / 4, 256, 0, stream>>>(xb, ln1_g + l * 512, ln1_b + l * 512, xb);
        // ---- MLP phase ----
        for (int c = 0; c < ncm; c++) {
            const size_t t0 = (size_t)c * chunk_m;
            const int grid = (chunk_m / 256) * 2;
            // h1 = relu(x @ w1 + b1)   (tpb = 2048/256/2 = 4)
            gemm256<2, 512, 512, 2048, 4><<<dim3(grid), 512, 131072, stream>>>(
                xb + t0 * 512, ww1t + (size_t)l * 1048576, h1c,
                b1 + l * 2048, nullptr);
            // x = h1 @ w2 + b2 + x   (in-place residual; K=2048, tpb=1)
            gemm256<1, 2048, 2048, 512, 1><<<dim3(grid), 512, 131072, stream>>>(
                h1c, ww2t + (size_t)l * 1048576, xb + t0 * 512,
                b2 + l * 512, xb + t0 * 512);
        }
        // x = LN2(x)  (in-place)
        ln_k<<<NTOK / 4, 256, 0, stream>>>(xb, ln2_g + l * 512, ln2_b + l * 512, xb);
    }

    // logits = x @ lm_w + lm_b  (N padded to 128, masked fp32 store)
    gemm_bt<3><<<dim3(1, 256), 512, 0, stream>>>(
        xb, wlmt, out, lm_b, nullptr, 512, 512, 128, VOCAB);
}

// Round 4
// 4585.748 us; speedup vs baseline: 1.1464x; 1.1464x over previous
//
#include <hip/hip_runtime.h>
#include <hip/hip_bf16.h>
#include <math.h>

// Problem constants
#define NTOK  65536      // B*T
#define CDIM  512
#define NHEAD 8
#define HSZ   64
#define NLAYER 6
#define DFF   2048
#define VOCAB 65

typedef unsigned short u16;
typedef __attribute__((ext_vector_type(8))) __bf16 bf16x8;
typedef __attribute__((ext_vector_type(4))) float f32x4;
typedef __attribute__((ext_vector_type(16))) float f32x16;
typedef __attribute__((ext_vector_type(8))) unsigned short ushort8;

__device__ __forceinline__ float b2f(u16 u) {
    union { unsigned int i; float f; } x; x.i = ((unsigned int)u) << 16; return x.f;
}
__device__ __forceinline__ u16 f2b(float f) {
    union { float f; unsigned int i; } x; x.f = f;
    unsigned int r = x.i + 0x7fffu + ((x.i >> 16) & 1u);   // RNE
    return (u16)(r >> 16);
}

__device__ __forceinline__ void async16(const u16* g, u16* l) {
    __builtin_amdgcn_global_load_lds(
        (const __attribute__((address_space(1))) void*)g,
        (__attribute__((address_space(3))) void*)l, 16, 0, 0);
}

// ---------------------------------------------------------------------------
// R11: R0 baseline structure (2-barrier, 256x128 tile, 2048-block grid,
// 3 blocks/CU class) with ONLY the inner compute changed:
//   1. mfma_f32_32x32x16_bf16, swapped operands: 16 MFMAs/wave-K-step vs 64.
//      (R0-R3 post-mortem: every schedule landed at 27-28% MfmaUtil with all
//      pipes <=28% busy -> convoy/issue signature. Instruction mix is the one
//      thing never varied. 32x32 ubench 2382 TF vs 16x16's 2075.)
//   2. LDS [row][64] layout + XOR swizzle granule^(row&7), both-sides
//      (linear gload_lds dest + pre-swizzled global src + swizzled read) —
//      the exact pair measured conflict-free in R1/R2. Kills R0's 8.4M
//      SQ_LDS_BANK_CONFLICT without structural churn.
// Everything else (grid, XCD mapping, chunking, barriers, epilogue EPI
// semantics, K order ascending) identical to the 3910-us R0 baseline.
// Layouts: C/D of 32x32x16 (verified m74/m101): col=lane&31,
// row=(reg&3)+8*(reg>>2)+4*(lane>>5). A/B: row=lane&31, k=(lane>>5)*8+e
// (generalizes the proven 16x16x32 pattern row=lane&15, k=(lane>>4)*8+e).
// Swapped mfma(B,A) -> D "col"=A-row, D reg-index sweeps B-cols in 4 groups
// of 4 consecutive -> uint2 stores as before.
// ---------------------------------------------------------------------------
template<int EPI>
__global__ __launch_bounds__(512)
void gemm32(const u16* __restrict__ A, const u16* __restrict__ Bt,
            void* __restrict__ Cout, const float* __restrict__ bias,
            const u16* __restrict__ res, int K, int lda, int N)
{
    __shared__ u16 lA[256 * 64];   // 32 KB, [row][64] k-contiguous
    __shared__ u16 lB[128 * 64];   // 16 KB
    const int tid  = threadIdx.x;

    // XCD-aware swizzle (R0 mapping; concurrent footprint ~6 A-stripes/XCD)
    const int Nx = gridDim.x;
    const int id = blockIdx.y * Nx + blockIdx.x;
    const int xcd = id & 7;
    const int j0  = id >> 3;
    const int mt  = xcd + 8 * (j0 / Nx);
    const int nt  = j0 - (j0 / Nx) * Nx;
    const int m0  = mt * 256;
    const int n0  = nt * 128;

    const int lane = tid & 63;
    const int wv   = tid >> 6;         // 8 waves
    const int wr   = (wv >> 1) * 64;   // wave row offset (0,64,128,192)
    const int wc   = (wv & 1) * 64;    // wave col offset (0,64)
    const int l31  = lane & 31;
    const int hi5  = lane >> 5;
    const int sw   = lane & 7;         // read-side row swizzle key (row&7 == lane&7)

    f32x16 acc[2][2] = {};             // acc[cb][rb], swapped-operand layout

    // staging: thread -> (row = srow (+64*rb), swizzled granule sg)
    const int srow = tid >> 3;                         // 0..63
    const int sg   = ((tid & 7) ^ (srow & 7)) * 8;     // pre-swizzled global granule
    const u16* pA  = A  + (size_t)(m0 + srow) * lda + sg;
    const u16* pB  = Bt + (size_t)(n0 + srow) * K + sg;
    u16* lAt = &lA[(size_t)tid * 8];
    u16* lBt = &lB[(size_t)tid * 8];
    const size_t a64 = (size_t)64 * lda, b64 = (size_t)64 * K;

    for (int k0 = 0; k0 < K; k0 += 64) {
        async16(pA + k0,           lAt);               // A rows   0..63
        async16(pA + a64 + k0,     lAt + 4096);        // A rows  64..127
        async16(pA + 2 * a64 + k0, lAt + 8192);        // A rows 128..191
        async16(pA + 3 * a64 + k0, lAt + 12288);       // A rows 192..255
        async16(pB + k0,           lBt);               // B rows   0..63
        async16(pB + b64 + k0,     lBt + 4096);        // B rows  64..127
        __syncthreads();   // drains vmcnt -> LDS valid

        bf16x8 af[2][4], bfr[2][4];
#pragma unroll
        for (int rb = 0; rb < 2; rb++)
#pragma unroll
            for (int kc = 0; kc < 4; kc++)
                af[rb][kc] = *(const bf16x8*)(const void*)
                    &lA[(wr + rb * 32 + l31) * 64 + (((kc * 2 + hi5) ^ sw) * 8)];
#pragma unroll
        for (int cb = 0; cb < 2; cb++)
#pragma unroll
            for (int kc = 0; kc < 4; kc++)
                bfr[cb][kc] = *(const bf16x8*)(const void*)
                    &lB[(wc + cb * 32 + l31) * 64 + (((kc * 2 + hi5) ^ sw) * 8)];

#pragma unroll
        for (int kc = 0; kc < 4; kc++)
#pragma unroll
            for (int cb = 0; cb < 2; cb++)
#pragma unroll
                for (int rb = 0; rb < 2; rb++)
                    acc[cb][rb] = __builtin_amdgcn_mfma_f32_32x32x16_bf16(
                        bfr[cb][kc], af[rb][kc], acc[cb][rb], 0, 0, 0);
        __syncthreads();   // all reads done before next stage overwrites
    }

    // epilogue (swapped 32x32 layout): row = wr + rb*32 + l31,
    // cols = wc + cb*32 + cg*8 + hi5*4 + r   (r = reg&3, reg = cg*4+r)
#pragma unroll
    for (int rb = 0; rb < 2; rb++) {
        const int row = m0 + wr + rb * 32 + l31;
#pragma unroll
        for (int cb = 0; cb < 2; cb++) {
#pragma unroll
            for (int cg = 0; cg < 4; cg++) {
                const int colb = n0 + wc + cb * 32 + cg * 8 + hi5 * 4;
                float v[4];
#pragma unroll
                for (int r = 0; r < 4; r++) v[r] = acc[cb][rb][cg * 4 + r];
                if (EPI == 1 || EPI == 2) {
                    const f32x4 b4 = *(const f32x4*)(const void*)&bias[colb];
#pragma unroll
                    for (int r = 0; r < 4; r++) v[r] += b4[r];
                }
                if (EPI == 1) {
                    const uint2 rv = *(const uint2*)(const void*)&res[(size_t)row * N + colb];
                    v[0] += b2f((u16)(rv.x & 0xffffu));
                    v[1] += b2f((u16)(rv.x >> 16));
                    v[2] += b2f((u16)(rv.y & 0xffffu));
                    v[3] += b2f((u16)(rv.y >> 16));
                }
                if (EPI == 2) {
#pragma unroll
                    for (int r = 0; r < 4; r++) v[r] = fmaxf(v[r], 0.f);
                }
                uint2 o;
                o.x = (unsigned)f2b(v[0]) | ((unsigned)f2b(v[1]) << 16);
                o.y = (unsigned)f2b(v[2]) | ((unsigned)f2b(v[3]) << 16);
                *(uint2*)(void*)&((u16*)Cout)[(size_t)row * N + colb] = o;
            }
        }
    }
}

// ---------------------------------------------------------------------------
// Legacy 256x128 16x16x32 GEMM — kept for the LM head (EPI 3: +bias -> f32,
// masked col < Nout). Proven R0 kernel, untouched.
// ---------------------------------------------------------------------------
template<int EPI>
__global__ __launch_bounds__(512)
void gemm_bt(const u16* __restrict__ A, const u16* __restrict__ Bt,
             void* __restrict__ Cout, const float* __restrict__ bias,
             const u16* __restrict__ res, int K, int lda, int N, int Nout)
{
    __shared__ u16 lA[2 * 256 * 32];
    __shared__ u16 lB[2 * 128 * 32];
    const int tid  = threadIdx.x;

    const int Nx = gridDim.x;
    const int id = blockIdx.y * Nx + blockIdx.x;
    const int xcd = id & 7;
    const int j0  = id >> 3;
    const int mt  = xcd + 8 * (j0 / Nx);
    const int nt  = j0 - (j0 / Nx) * Nx;
    const int m0  = mt * 256;
    const int n0  = nt * 128;

    const int lane = tid & 63;
    const int wv   = tid >> 6;
    const int wr   = (wv >> 1) * 64;
    const int wc   = (wv & 1) * 64;
    const int r16  = lane & 15;
    const int quad = lane >> 4;

    f32x4 acc[4][4] = {};

    const int srow = tid >> 2, skseg = (tid & 3) * 8;
    const u16* pA  = A  + (size_t)(m0 + srow) * lda + skseg;
    const u16* pA2 = pA + (size_t)128 * lda;
    const u16* pB  = Bt + (size_t)(n0 + srow) * K + skseg;
    u16* lAt = &lA[(size_t)tid * 8];
    u16* lBt = &lB[(size_t)tid * 8];

    for (int k0 = 0; k0 < K; k0 += 64) {
        async16(pA  + k0,      lAt);
        async16(pA2 + k0,      lAt + 4096);
        async16(pA  + k0 + 32, lAt + 8192);
        async16(pA2 + k0 + 32, lAt + 12288);
        async16(pB  + k0,      lBt);
        async16(pB  + k0 + 32, lBt + 4096);
        __syncthreads();

#pragma unroll
        for (int s = 0; s < 2; s++) {
            const u16* bA = &lA[s * 8192];
            const u16* bB = &lB[s * 4096];
            bf16x8 af[4], bfr[4];
#pragma unroll
            for (int i = 0; i < 4; i++)
                af[i] = *(const bf16x8*)(const void*)&bA[(wr + i * 16 + r16) * 32 + quad * 8];
#pragma unroll
            for (int j = 0; j < 4; j++)
                bfr[j] = *(const bf16x8*)(const void*)&bB[(wc + j * 16 + r16) * 32 + quad * 8];
#pragma unroll
            for (int j = 0; j < 4; j++)
#pragma unroll
                for (int i = 0; i < 4; i++)
                    acc[j][i] = __builtin_amdgcn_mfma_f32_16x16x32_bf16(bfr[j], af[i], acc[j][i], 0, 0, 0);
        }
        __syncthreads();
    }

#pragma unroll
    for (int i = 0; i < 4; i++) {
        const int row = m0 + wr + i * 16 + r16;
#pragma unroll
        for (int j = 0; j < 4; j++) {
            const int colb = n0 + wc + j * 16 + quad * 4;
            float v[4];
#pragma unroll
            for (int r = 0; r < 4; r++) v[r] = acc[j][i][r];
            if (EPI == 3) {
#pragma unroll
                for (int r = 0; r < 4; r++) {
                    const int col = colb + r;
                    if (col < Nout)
                        ((float*)Cout)[(size_t)row * Nout + col] = v[r] + bias[col];
                }
            } else {
                uint2 o;
                o.x = (unsigned)f2b(v[0]) | ((unsigned)f2b(v[1]) << 16);
                o.y = (unsigned)f2b(v[2]) | ((unsigned)f2b(v[3]) << 16);
                *(uint2*)(void*)&((u16*)Cout)[(size_t)row * N + colb] = o;
            }
        }
    }
}

// ---------------------------------------------------------------------------
// Attention: one wave per (b,h). T=8, HS=64. qkv layout [token][q|k|v, h*64+d].
// IN-PLACE into q-slot. NOTE: reference scale = C^-0.5 = 512^-0.5.
// ---------------------------------------------------------------------------
__global__ __launch_bounds__(256)
void attn_k(u16* __restrict__ qkv)
{
    __shared__ float sq[4][8][65], sk[4][8][65], sv[4][8][65], sp[4][64];
    const int w = threadIdx.x >> 6, lane = threadIdx.x & 63;
    const int unit = blockIdx.x * 4 + w;
    const int b = unit >> 3, h = unit & 7;
    const size_t base = (size_t)b * 8 * 1536 + h * 64;
    {
        const int t = lane >> 3, d0 = (lane & 7) * 8;
        const ushort8 q8 = *(const ushort8*)(const void*)&qkv[base + t * 1536 + d0];
        const ushort8 k8 = *(const ushort8*)(const void*)&qkv[base + t * 1536 + 512 + d0];
        const ushort8 v8 = *(const ushort8*)(const void*)&qkv[base + t * 1536 + 1024 + d0];
#pragma unroll
        for (int i = 0; i < 8; i++) {
            sq[w][t][d0 + i] = b2f(q8[i]);
            sk[w][t][d0 + i] = b2f(k8[i]);
            sv[w][t][d0 + i] = b2f(v8[i]);
        }
    }
    __syncthreads();
    const int t = lane >> 3, s = lane & 7;
    float sc = -1e30f;
    if (s <= t) {
        float d = 0.f;
#pragma unroll
        for (int c = 0; c < 64; c++) d += sq[w][t][c] * sk[w][s][c];
        sc = d * 0.04419417382415922f;          // 512^-0.5
    }
    float mx = sc;
#pragma unroll
    for (int m = 1; m < 8; m <<= 1) mx = fmaxf(mx, __shfl_xor(mx, m, 8));
    float e = __expf(sc - mx);
    if (s > t) e = 0.f;
    float sum = e;
#pragma unroll
    for (int m = 1; m < 8; m <<= 1) sum += __shfl_xor(sum, m, 8);
    sp[w][lane] = e / sum;
    __syncthreads();
    {
        const int tt = lane >> 3, d0 = (lane & 7) * 8;
        float a[8] = {};
#pragma unroll
        for (int ss = 0; ss < 8; ss++) {
            const float p = sp[w][tt * 8 + ss];
#pragma unroll
            for (int i = 0; i < 8; i++) a[i] += p * sv[w][ss][d0 + i];
        }
        ushort8 o;
#pragma unroll
        for (int i = 0; i < 8; i++) o[i] = f2b(a[i]);
        *(ushort8*)(void*)&qkv[base + tt * 1536 + d0] = o;
    }
}

// ---------------------------------------------------------------------------
// LayerNorm: wave per token, 8 elems/lane, shuffle reduction. In-place OK.
// ---------------------------------------------------------------------------
__global__ __launch_bounds__(256)
void ln_k(const u16* __restrict__ y, const float* __restrict__ g,
          const float* __restrict__ be, u16* __restrict__ x)
{
    const int w = threadIdx.x >> 6, lane = threadIdx.x & 63;
    const size_t tok = (size_t)blockIdx.x * 4 + w;
    const u16* row = y + tok * 512 + lane * 8;
    ushort8 raw = *(const ushort8*)(const void*)row;
    float v[8];
#pragma unroll
    for (int i = 0; i < 8; i++) v[i] = b2f(raw[i]);
    float s = 0.f;
#pragma unroll
    for (int i = 0; i < 8; i++) s += v[i];
#pragma unroll
    for (int m = 1; m < 64; m <<= 1) s += __shfl_xor(s, m, 64);
    const float mu = s * (1.f / 512.f);
    float q = 0.f;
#pragma unroll
    for (int i = 0; i < 8; i++) { float d = v[i] - mu; q += d * d; }
#pragma unroll
    for (int m = 1; m < 64; m <<= 1) q += __shfl_xor(q, m, 64);
    const float inv = rsqrtf(q * (1.f / 512.f) + 1e-5f);
    f32x4 g0  = *(const f32x4*)(const void*)&g[lane * 8];
    f32x4 g1  = *(const f32x4*)(const void*)&g[lane * 8 + 4];
    f32x4 b0  = *(const f32x4*)(const void*)&be[lane * 8];
    f32x4 b1v = *(const f32x4*)(const void*)&be[lane * 8 + 4];
    ushort8 o;
#pragma unroll
    for (int i = 0; i < 4; i++) o[i]     = f2b((v[i] - mu) * inv * g0[i] + b0[i]);
#pragma unroll
    for (int i = 0; i < 4; i++) o[i + 4] = f2b((v[i + 4] - mu) * inv * g1[i] + b1v[i]);
    *(ushort8*)(void*)&x[tok * 512 + lane * 8] = o;
}

// ---------------------------------------------------------------------------
// Embedding: vectorized. thread -> (token, 8-col segment).
// ---------------------------------------------------------------------------
__global__ __launch_bounds__(256)
void embed_k(const int* __restrict__ idx, const float* __restrict__ tokt,
             const float* __restrict__ pos, u16* __restrict__ xb)
{
    const int gid = blockIdx.x * 256 + threadIdx.x;
    const int tk = gid >> 6, seg = (gid & 63) * 8;
    const int t = tk & 7;
    const int ix = idx[tk];
    const f32x4 a0 = *(const f32x4*)(const void*)&tokt[(size_t)ix * 512 + seg];
    const f32x4 a1 = *(const f32x4*)(const void*)&tokt[(size_t)ix * 512 + seg + 4];
    const f32x4 p0 = *(const f32x4*)(const void*)&pos[t * 512 + seg];
    const f32x4 p1 = *(const f32x4*)(const void*)&pos[t * 512 + seg + 4];
    ushort8 o;
#pragma unroll
    for (int i = 0; i < 4; i++) o[i]     = f2b(a0[i] + p0[i]);
#pragma unroll
    for (int i = 0; i < 4; i++) o[i + 4] = f2b(a1[i] + p1[i]);
    *(ushort8*)(void*)&xb[(size_t)tk * 512 + seg] = o;
}

// ---------------------------------------------------------------------------
// Weight converts (fp32 -> bf16 B^T layouts), LDS-tiled transposes
// ---------------------------------------------------------------------------
__global__ __launch_bounds__(256)
void conv_t2_k(const float* __restrict__ in, u16* __restrict__ out, int K, int N)
{
    __shared__ float t[32][33];
    const int tx = threadIdx.x & 31, ty4 = (threadIdx.x >> 5) * 4;
    const int n0 = blockIdx.x * 32, k0 = blockIdx.y * 32, l = blockIdx.z;
    const size_t per = (size_t)K * N;
    const float* src = in + l * per;
#pragma unroll
    for (int r = 0; r < 4; r++)
        t[ty4 + r][tx] = src[(size_t)(k0 + ty4 + r) * N + n0 + tx];
    __syncthreads();
    u16* dst = out + l * per;
#pragma unroll
    for (int r = 0; r < 4; r++)
        dst[(size_t)(n0 + ty4 + r) * K + k0 + tx] = f2b(t[tx][ty4 + r]);
}

__global__ __launch_bounds__(256)
void conv_qkv2_k(const float* __restrict__ wq, const float* __restrict__ wk,
                 const float* __restrict__ wv, u16* __restrict__ out)
{
    __shared__ float t[32][33];
    const int tx = threadIdx.x & 31, ty4 = (threadIdx.x >> 5) * 4;
    const int c0 = blockIdx.x * 32, d0 = blockIdx.y * 32;
    const int z = blockIdx.z;
    const int sel = z / 48, rem = z - sel * 48;
    const int l = rem >> 3, h = rem & 7;
    const float* src = (sel == 0) ? wq : (sel == 1) ? wk : wv;
    const float* sb = src + (((size_t)l * 8 + h) * 512) * 64;
#pragma unroll
    for (int r = 0; r < 4; r++)
        t[ty4 + r][tx] = sb[(size_t)(c0 + ty4 + r) * 64 + d0 + tx];
    __syncthreads();
    u16* dst = out + (size_t)l * 786432 + (size_t)(sel * 512 + h * 64 + d0) * 512;
#pragma unroll
    for (int r = 0; r < 4; r++)
        dst[(size_t)(ty4 + r) * 512 + c0 + tx] = f2b(t[tx][ty4 + r]);
}

__global__ __launch_bounds__(256)
void conv_lm_k(const float* __restrict__ lm_w, u16* __restrict__ out)
{
    int gid = blockIdx.x * 256 + threadIdx.x;
    int n = gid >> 9, c = gid & 511;
    out[gid] = (n < VOCAB) ? f2b(lm_w[(size_t)c * VOCAB + n]) : (u16)0;
}

// ---------------------------------------------------------------------------
extern "C" void kernel_launch(void* const* d_in, const int* in_sizes, int n_in,
                              void* d_out, int out_size, void* d_ws, size_t ws_size,
                              hipStream_t stream)
{
    const int*   idx    = (const int*)  d_in[0];
    const float* tokt   = (const float*)d_in[1];
    const float* post   = (const float*)d_in[2];
    const float* wq     = (const float*)d_in[3];
    const float* wk     = (const float*)d_in[4];
    const float* wvp    = (const float*)d_in[5];
    const float* proj_w = (const float*)d_in[6];
    const float* proj_b = (const float*)d_in[7];
    const float* w1     = (const float*)d_in[8];
    const float* b1     = (const float*)d_in[9];
    const float* w2     = (const float*)d_in[10];
    const float* b2     = (const float*)d_in[11];
    const float* ln1_g  = (const float*)d_in[12];
    const float* ln1_b  = (const float*)d_in[13];
    const float* ln2_g  = (const float*)d_in[14];
    const float* ln2_b  = (const float*)d_in[15];
    const float* lm_w   = (const float*)d_in[16];
    const float* lm_b   = (const float*)d_in[17];
    float* out = (float*)d_out;

    char* ws = (char*)d_ws;
    u16* wqkvt = (u16*)(ws + 0);                     //  9,437,184
    u16* wprjt = (u16*)(ws + 9437184);               //  3,145,728
    u16* ww1t  = (u16*)(ws + 12582912);              // 12,582,912
    u16* ww2t  = (u16*)(ws + 25165824);              // 12,582,912
    u16* wlmt  = (u16*)(ws + 37748736);              //    131,072
    u16* xb    = (u16*)(ws + 37879808);              // 67,108,864  residual
    char* big  = ws + 104988672;                     // transient

    const size_t fixed_bytes = 104988672ull;
    const size_t avail = (ws_size > fixed_bytes) ? (ws_size - fixed_bytes) : 0;
    int chunk_a = 8192, chunk_m = 8192;
    const int cands[3] = {65536, 32768, 16384};
    for (int i = 0; i < 3; i++)
        if ((size_t)cands[i] * 3072ull <= avail) { chunk_a = cands[i]; break; }
    for (int i = 0; i < 3; i++)
        if ((size_t)cands[i] * 4096ull <= avail) { chunk_m = cands[i]; break; }
    const int nca = NTOK / chunk_a, ncm = NTOK / chunk_m;
    u16* qkvc = (u16*)big;                           // chunk_a x 1536
    u16* h1c  = (u16*)big;                           // chunk_m x 2048

    conv_qkv2_k<<<dim3(16, 2, 144), 256, 0, stream>>>(wq, wk, wvp, wqkvt);
    conv_t2_k  <<<dim3(16, 16, 6), 256, 0, stream>>>(proj_w, wprjt, 512, 512);
    conv_t2_k  <<<dim3(64, 16, 6), 256, 0, stream>>>(w1, ww1t, 512, 2048);
    conv_t2_k  <<<dim3(16, 64, 6), 256, 0, stream>>>(w2, ww2t, 2048, 512);
    conv_lm_k  <<<128 * 512 / 256, 256, 0, stream>>>(lm_w, wlmt);

    embed_k<<<NTOK * 64 / 256, 256, 0, stream>>>(idx, tokt, post, xb);

    for (int l = 0; l < NLAYER; l++) {
        // ---- attention phase ----
        for (int c = 0; c < nca; c++) {
            const size_t t0 = (size_t)c * chunk_a;
            // qkv = x @ Wqkv
            gemm32<0><<<dim3(12, chunk_a / 256), 512, 0, stream>>>(
                xb + t0 * 512, wqkvt + (size_t)l * 786432, qkvc,
                nullptr, nullptr, 512, 512, 1536);
            // attention, in-place into q-slot of qkvc
            attn_k<<<chunk_a / 4, 256, 0, stream>>>(qkvc);
            // x = attno @ proj_w + proj_b + x   (A = q-slot, lda=1536)
            gemm32<1><<<dim3(4, chunk_a / 256), 512, 0, stream>>>(
                qkvc, wprjt + (size_t)l * 262144, xb + t0 * 512,
                proj_b + l * 512, xb + t0 * 512, 512, 1536, 512);
        }
        // x = LN1(x)  (in-place)
        ln_k<<<NTOK / 4, 256, 0, stream>>>(xb, ln1_g + l * 512, ln1_b + l * 512, xb);
        // ---- MLP phase ----
        for (int c = 0; c < ncm; c++) {
            const size_t t0 = (size_t)c * chunk_m;
            // h1 = relu(x @ w1 + b1)
            gemm32<2><<<dim3(16, chunk_m / 256), 512, 0, stream>>>(
                xb + t0 * 512, ww1t + (size_t)l * 1048576, h1c,
                b1 + l * 2048, nullptr, 512, 512, 2048);
            // x = h1 @ w2 + b2 + x   (in-place residual)
            gemm32<1><<<dim3(4, chunk_m / 256), 512, 0, stream>>>(
                h1c, ww2t + (size_t)l * 1048576, xb + t0 * 512,
                b2 + l * 512, xb + t0 * 512, 2048, 2048, 512);
        }
        // x = LN2(x)  (in-place)
        ln_k<<<NTOK / 4, 256, 0, stream>>>(xb, ln2_g + l * 512, ln2_b + l * 512, xb);
    }

    // logits = x @ lm_w + lm_b  (N padded to 128, masked fp32 store)
    gemm_bt<3><<<dim3(1, 256), 512, 0, stream>>>(
        xb, wlmt, out, lm_b, nullptr, 512, 512, 128, VOCAB);
}

// Round 5
// 4076.920 us; speedup vs baseline: 1.2895x; 1.1248x over previous
//
#include <hip/hip_runtime.h>
#include <hip/hip_bf16.h>
#include <math.h>

// Problem constants
#define NTOK  65536      // B*T
#define CDIM  512
#define NHEAD 8
#define HSZ   64
#define NLAYER 6
#define DFF   2048
#define VOCAB 65

typedef unsigned short u16;
typedef __attribute__((ext_vector_type(8))) __bf16 bf16x8;
typedef __attribute__((ext_vector_type(4))) float f32x4;
typedef __attribute__((ext_vector_type(8))) unsigned short ushort8;

__device__ __forceinline__ float b2f(u16 u) {
    union { unsigned int i; float f; } x; x.i = ((unsigned int)u) << 16; return x.f;
}
__device__ __forceinline__ u16 f2b(float f) {
    union { float f; unsigned int i; } x; x.f = f;
    unsigned int r = x.i + 0x7fffu + ((x.i >> 16) & 1u);   // RNE
    return (u16)(r >> 16);
}

__device__ __forceinline__ void async16(const u16* g, u16* l) {
    __builtin_amdgcn_global_load_lds(
        (const __attribute__((address_space(1))) void*)g,
        (__attribute__((address_space(3))) void*)l, 16, 0, 0);
}

// ---------------------------------------------------------------------------
// R12: R0 baseline (2-barrier, 256x128, 48KB LDS, 3 blocks/CU, 16x16x32 MFMA)
// + the ONE proven-zero-conflict LDS scheme, nothing else.
// R4 attribution: [row][64]+XOR with l31/hi5 read grouping = 2 conflict-cyc
// per b128 read (8.4M, same as R0's [row][32]); R1/R2's r16/quad grouping on
// the SAME layout measured ZERO. This kernel = R0 structure with:
//   - LDS [row][64] (BK=64 flat), 48KB total -> 3 blocks/CU preserved
//   - staging: srow=tid>>3, slot=tid&7, global granule (tid&7)^(srow&7)
//     (linear gload_lds dest + pre-swizzled source, rule 21)
//   - reads: granule = (s*4+quad) ^ (r16&7)  [R1's exact zero-conflict form]
//   - two K=32 sub-steps (s=0,1) keep fragment live-range = R0 (~60 VGPR,
//     occupancy-critical). K order per acc identical to R0 -> bitwise-same.
// Everything else (grid, XCD mapping, chunking, epilogues, attn, LN) = R0.
// ---------------------------------------------------------------------------
template<int EPI>
__global__ __launch_bounds__(512)
void gemm_bt(const u16* __restrict__ A, const u16* __restrict__ Bt,
             void* __restrict__ Cout, const float* __restrict__ bias,
             const u16* __restrict__ res, int K, int lda, int N, int Nout)
{
    __shared__ u16 lA[256 * 64];   // 32 KB, [row][64] k-contiguous
    __shared__ u16 lB[128 * 64];   // 16 KB
    const int tid  = threadIdx.x;

    // XCD-aware swizzle
    const int Nx = gridDim.x;
    const int id = blockIdx.y * Nx + blockIdx.x;
    const int xcd = id & 7;
    const int j0  = id >> 3;
    const int mt  = xcd + 8 * (j0 / Nx);
    const int nt  = j0 - (j0 / Nx) * Nx;
    const int m0  = mt * 256;
    const int n0  = nt * 128;

    const int lane = tid & 63;
    const int wv   = tid >> 6;         // 0..7
    const int wr   = (wv >> 1) * 64;   // wave row offset (0,64,128,192)
    const int wc   = (wv & 1) * 64;    // wave col offset (0,64)
    const int r16  = lane & 15;
    const int quad = lane >> 4;
    const int sw8  = r16 & 7;          // read-side swizzle key (= row&7)

    f32x4 acc[4][4] = {};              // acc[j][i], swapped-operand layout

    // staging: thread -> (row = srow + 64*chunk, granule slot tid&7)
    const int srow = tid >> 3;                         // 0..63
    const int sg   = ((tid & 7) ^ (srow & 7)) * 8;     // pre-swizzled global granule
    const u16* pA  = A  + (size_t)(m0 + srow) * lda + sg;
    const u16* pB  = Bt + (size_t)(n0 + srow) * K + sg;
    u16* lAt = &lA[(size_t)tid * 8];
    u16* lBt = &lB[(size_t)tid * 8];
    const size_t a64 = (size_t)64 * lda, b64 = (size_t)64 * K;

    // per-lane read offsets (u16 units): granule (s*4+quad)^sw8 within 64-wide row
    const int gA0 = ((0 * 4 + quad) ^ sw8) * 8;
    const int gA1 = ((1 * 4 + quad) ^ sw8) * 8;

    for (int k0 = 0; k0 < K; k0 += 64) {
        async16(pA + k0,           lAt);               // A rows   0..63
        async16(pA + a64 + k0,     lAt + 4096);        // A rows  64..127
        async16(pA + 2 * a64 + k0, lAt + 8192);        // A rows 128..191
        async16(pA + 3 * a64 + k0, lAt + 12288);       // A rows 192..255
        async16(pB + k0,           lBt);               // B rows   0..63
        async16(pB + b64 + k0,     lBt + 4096);        // B rows  64..127
        __syncthreads();   // drains vmcnt -> LDS valid

#pragma unroll
        for (int s = 0; s < 2; s++) {
            const int g = s ? gA1 : gA0;
            bf16x8 af[4], bfr[4];
#pragma unroll
            for (int i = 0; i < 4; i++)
                af[i] = *(const bf16x8*)(const void*)&lA[(wr + i * 16 + r16) * 64 + g];
#pragma unroll
            for (int j = 0; j < 4; j++)
                bfr[j] = *(const bf16x8*)(const void*)&lB[(wc + j * 16 + r16) * 64 + g];
#pragma unroll
            for (int j = 0; j < 4; j++)
#pragma unroll
                for (int i = 0; i < 4; i++)
                    acc[j][i] = __builtin_amdgcn_mfma_f32_16x16x32_bf16(bfr[j], af[i], acc[j][i], 0, 0, 0);
        }
        __syncthreads();   // all reads done before next stage overwrites
    }

    // epilogue (swapped layout): row = wr+i*16+r16, cols = wc+j*16+quad*4+r
#pragma unroll
    for (int i = 0; i < 4; i++) {
        const int row = m0 + wr + i * 16 + r16;
#pragma unroll
        for (int j = 0; j < 4; j++) {
            const int colb = n0 + wc + j * 16 + quad * 4;
            float v[4];
#pragma unroll
            for (int r = 0; r < 4; r++) v[r] = acc[j][i][r];
            if (EPI == 1 || EPI == 2) {
                const f32x4 b4 = *(const f32x4*)(const void*)&bias[colb];
#pragma unroll
                for (int r = 0; r < 4; r++) v[r] += b4[r];
            }
            if (EPI == 1) {
                const uint2 rv = *(const uint2*)(const void*)&res[(size_t)row * N + colb];
                v[0] += b2f((u16)(rv.x & 0xffffu));
                v[1] += b2f((u16)(rv.x >> 16));
                v[2] += b2f((u16)(rv.y & 0xffffu));
                v[3] += b2f((u16)(rv.y >> 16));
            }
            if (EPI == 2) {
#pragma unroll
                for (int r = 0; r < 4; r++) v[r] = fmaxf(v[r], 0.f);
            }
            if (EPI == 3) {
#pragma unroll
                for (int r = 0; r < 4; r++) {
                    const int col = colb + r;
                    if (col < Nout)
                        ((float*)Cout)[(size_t)row * Nout + col] = v[r] + bias[col];
                }
            } else {
                uint2 o;
                o.x = (unsigned)f2b(v[0]) | ((unsigned)f2b(v[1]) << 16);
                o.y = (unsigned)f2b(v[2]) | ((unsigned)f2b(v[3]) << 16);
                *(uint2*)(void*)&((u16*)Cout)[(size_t)row * N + colb] = o;
            }
        }
    }
}

// ---------------------------------------------------------------------------
// Attention: one wave per (b,h). T=8, HS=64. qkv layout [token][q|k|v, h*64+d].
// IN-PLACE into q-slot. NOTE: reference scale = C^-0.5 = 512^-0.5.
// ---------------------------------------------------------------------------
__global__ __launch_bounds__(256)
void attn_k(u16* __restrict__ qkv)
{
    __shared__ float sq[4][8][65], sk[4][8][65], sv[4][8][65], sp[4][64];
    const int w = threadIdx.x >> 6, lane = threadIdx.x & 63;
    const int unit = blockIdx.x * 4 + w;
    const int b = unit >> 3, h = unit & 7;
    const size_t base = (size_t)b * 8 * 1536 + h * 64;
    {
        const int t = lane >> 3, d0 = (lane & 7) * 8;
        const ushort8 q8 = *(const ushort8*)(const void*)&qkv[base + t * 1536 + d0];
        const ushort8 k8 = *(const ushort8*)(const void*)&qkv[base + t * 1536 + 512 + d0];
        const ushort8 v8 = *(const ushort8*)(const void*)&qkv[base + t * 1536 + 1024 + d0];
#pragma unroll
        for (int i = 0; i < 8; i++) {
            sq[w][t][d0 + i] = b2f(q8[i]);
            sk[w][t][d0 + i] = b2f(k8[i]);
            sv[w][t][d0 + i] = b2f(v8[i]);
        }
    }
    __syncthreads();
    const int t = lane >> 3, s = lane & 7;
    float sc = -1e30f;
    if (s <= t) {
        float d = 0.f;
#pragma unroll
        for (int c = 0; c < 64; c++) d += sq[w][t][c] * sk[w][s][c];
        sc = d * 0.04419417382415922f;          // 512^-0.5
    }
    float mx = sc;
#pragma unroll
    for (int m = 1; m < 8; m <<= 1) mx = fmaxf(mx, __shfl_xor(mx, m, 8));
    float e = __expf(sc - mx);
    if (s > t) e = 0.f;
    float sum = e;
#pragma unroll
    for (int m = 1; m < 8; m <<= 1) sum += __shfl_xor(sum, m, 8);
    sp[w][lane] = e / sum;
    __syncthreads();
    {
        const int tt = lane >> 3, d0 = (lane & 7) * 8;
        float a[8] = {};
#pragma unroll
        for (int ss = 0; ss < 8; ss++) {
            const float p = sp[w][tt * 8 + ss];
#pragma unroll
            for (int i = 0; i < 8; i++) a[i] += p * sv[w][ss][d0 + i];
        }
        ushort8 o;
#pragma unroll
        for (int i = 0; i < 8; i++) o[i] = f2b(a[i]);
        *(ushort8*)(void*)&qkv[base + tt * 1536 + d0] = o;   // q-slot
    }
}

// ---------------------------------------------------------------------------
// LayerNorm: wave per token, 8 elems/lane, shuffle reduction. In-place OK.
// ---------------------------------------------------------------------------
__global__ __launch_bounds__(256)
void ln_k(const u16* __restrict__ y, const float* __restrict__ g,
          const float* __restrict__ be, u16* __restrict__ x)
{
    const int w = threadIdx.x >> 6, lane = threadIdx.x & 63;
    const size_t tok = (size_t)blockIdx.x * 4 + w;
    const u16* row = y + tok * 512 + lane * 8;
    ushort8 raw = *(const ushort8*)(const void*)row;
    float v[8];
#pragma unroll
    for (int i = 0; i < 8; i++) v[i] = b2f(raw[i]);
    float s = 0.f;
#pragma unroll
    for (int i = 0; i < 8; i++) s += v[i];
#pragma unroll
    for (int m = 1; m < 64; m <<= 1) s += __shfl_xor(s, m, 64);
    const float mu = s * (1.f / 512.f);
    float q = 0.f;
#pragma unroll
    for (int i = 0; i < 8; i++) { float d = v[i] - mu; q += d * d; }
#pragma unroll
    for (int m = 1; m < 64; m <<= 1) q += __shfl_xor(q, m, 64);
    const float inv = rsqrtf(q * (1.f / 512.f) + 1e-5f);
    f32x4 g0  = *(const f32x4*)(const void*)&g[lane * 8];
    f32x4 g1  = *(const f32x4*)(const void*)&g[lane * 8 + 4];
    f32x4 b0  = *(const f32x4*)(const void*)&be[lane * 8];
    f32x4 b1v = *(const f32x4*)(const void*)&be[lane * 8 + 4];
    ushort8 o;
#pragma unroll
    for (int i = 0; i < 4; i++) o[i]     = f2b((v[i] - mu) * inv * g0[i] + b0[i]);
#pragma unroll
    for (int i = 0; i < 4; i++) o[i + 4] = f2b((v[i + 4] - mu) * inv * g1[i] + b1v[i]);
    *(ushort8*)(void*)&x[tok * 512 + lane * 8] = o;
}

// ---------------------------------------------------------------------------
// Embedding: vectorized. thread -> (token, 8-col segment).
// ---------------------------------------------------------------------------
__global__ __launch_bounds__(256)
void embed_k(const int* __restrict__ idx, const float* __restrict__ tokt,
             const float* __restrict__ pos, u16* __restrict__ xb)
{
    const int gid = blockIdx.x * 256 + threadIdx.x;    // < NTOK*64
    const int tk = gid >> 6, seg = (gid & 63) * 8;
    const int t = tk & 7;
    const int ix = idx[tk];
    const f32x4 a0 = *(const f32x4*)(const void*)&tokt[(size_t)ix * 512 + seg];
    const f32x4 a1 = *(const f32x4*)(const void*)&tokt[(size_t)ix * 512 + seg + 4];
    const f32x4 p0 = *(const f32x4*)(const void*)&pos[t * 512 + seg];
    const f32x4 p1 = *(const f32x4*)(const void*)&pos[t * 512 + seg + 4];
    ushort8 o;
#pragma unroll
    for (int i = 0; i < 4; i++) o[i]     = f2b(a0[i] + p0[i]);
#pragma unroll
    for (int i = 0; i < 4; i++) o[i + 4] = f2b(a1[i] + p1[i]);
    *(ushort8*)(void*)&xb[(size_t)tk * 512 + seg] = o;
}

// ---------------------------------------------------------------------------
// Weight converts (fp32 -> bf16 B^T layouts), LDS-tiled transposes
// ---------------------------------------------------------------------------
__global__ __launch_bounds__(256)
void conv_t2_k(const float* __restrict__ in, u16* __restrict__ out, int K, int N)
{
    __shared__ float t[32][33];
    const int tx = threadIdx.x & 31, ty4 = (threadIdx.x >> 5) * 4;
    const int n0 = blockIdx.x * 32, k0 = blockIdx.y * 32, l = blockIdx.z;
    const size_t per = (size_t)K * N;
    const float* src = in + l * per;
#pragma unroll
    for (int r = 0; r < 4; r++)
        t[ty4 + r][tx] = src[(size_t)(k0 + ty4 + r) * N + n0 + tx];
    __syncthreads();
    u16* dst = out + l * per;
#pragma unroll
    for (int r = 0; r < 4; r++)
        dst[(size_t)(n0 + ty4 + r) * K + k0 + tx] = f2b(t[tx][ty4 + r]);
}

__global__ __launch_bounds__(256)
void conv_qkv2_k(const float* __restrict__ wq, const float* __restrict__ wk,
                 const float* __restrict__ wv, u16* __restrict__ out)
{
    __shared__ float t[32][33];
    const int tx = threadIdx.x & 31, ty4 = (threadIdx.x >> 5) * 4;
    const int c0 = blockIdx.x * 32, d0 = blockIdx.y * 32;
    const int z = blockIdx.z;
    const int sel = z / 48, rem = z - sel * 48;
    const int l = rem >> 3, h = rem & 7;
    const float* src = (sel == 0) ? wq : (sel == 1) ? wk : wv;
    const float* sb = src + (((size_t)l * 8 + h) * 512) * 64;
#pragma unroll
    for (int r = 0; r < 4; r++)
        t[ty4 + r][tx] = sb[(size_t)(c0 + ty4 + r) * 64 + d0 + tx];
    __syncthreads();
    u16* dst = out + (size_t)l * 786432 + (size_t)(sel * 512 + h * 64 + d0) * 512;
#pragma unroll
    for (int r = 0; r < 4; r++)
        dst[(size_t)(ty4 + r) * 512 + c0 + tx] = f2b(t[tx][ty4 + r]);
}

__global__ __launch_bounds__(256)
void conv_lm_k(const float* __restrict__ lm_w, u16* __restrict__ out)
{
    int gid = blockIdx.x * 256 + threadIdx.x;        // < 128*512
    int n = gid >> 9, c = gid & 511;
    out[gid] = (n < VOCAB) ? f2b(lm_w[(size_t)c * VOCAB + n]) : (u16)0;
}

// ---------------------------------------------------------------------------
extern "C" void kernel_launch(void* const* d_in, const int* in_sizes, int n_in,
                              void* d_out, int out_size, void* d_ws, size_t ws_size,
                              hipStream_t stream)
{
    const int*   idx    = (const int*)  d_in[0];
    const float* tokt   = (const float*)d_in[1];
    const float* post   = (const float*)d_in[2];
    const float* wq     = (const float*)d_in[3];
    const float* wk     = (const float*)d_in[4];
    const float* wvp    = (const float*)d_in[5];
    const float* proj_w = (const float*)d_in[6];
    const float* proj_b = (const float*)d_in[7];
    const float* w1     = (const float*)d_in[8];
    const float* b1     = (const float*)d_in[9];
    const float* w2     = (const float*)d_in[10];
    const float* b2     = (const float*)d_in[11];
    const float* ln1_g  = (const float*)d_in[12];
    const float* ln1_b  = (const float*)d_in[13];
    const float* ln2_g  = (const float*)d_in[14];
    const float* ln2_b  = (const float*)d_in[15];
    const float* lm_w   = (const float*)d_in[16];
    const float* lm_b   = (const float*)d_in[17];
    float* out = (float*)d_out;

    char* ws = (char*)d_ws;
    u16* wqkvt = (u16*)(ws + 0);                     //  9,437,184
    u16* wprjt = (u16*)(ws + 9437184);               //  3,145,728
    u16* ww1t  = (u16*)(ws + 12582912);              // 12,582,912
    u16* ww2t  = (u16*)(ws + 25165824);              // 12,582,912
    u16* wlmt  = (u16*)(ws + 37748736);              //    131,072
    u16* xb    = (u16*)(ws + 37879808);              // 67,108,864  residual
    char* big  = ws + 104988672;                     // transient

    const size_t fixed_bytes = 104988672ull;
    const size_t avail = (ws_size > fixed_bytes) ? (ws_size - fixed_bytes) : 0;
    int chunk_a = 8192, chunk_m = 8192;
    const int cands[3] = {65536, 32768, 16384};
    for (int i = 0; i < 3; i++)
        if ((size_t)cands[i] * 3072ull <= avail) { chunk_a = cands[i]; break; }
    for (int i = 0; i < 3; i++)
        if ((size_t)cands[i] * 4096ull <= avail) { chunk_m = cands[i]; break; }
    const int nca = NTOK / chunk_a, ncm = NTOK / chunk_m;
    u16* qkvc = (u16*)big;                           // chunk_a x 1536
    u16* h1c  = (u16*)big;                           // chunk_m x 2048

    conv_qkv2_k<<<dim3(16, 2, 144), 256, 0, stream>>>(wq, wk, wvp, wqkvt);
    conv_t2_k  <<<dim3(16, 16, 6), 256, 0, stream>>>(proj_w, wprjt, 512, 512);
    conv_t2_k  <<<dim3(64, 16, 6), 256, 0, stream>>>(w1, ww1t, 512, 2048);
    conv_t2_k  <<<dim3(16, 64, 6), 256, 0, stream>>>(w2, ww2t, 2048, 512);
    conv_lm_k  <<<128 * 512 / 256, 256, 0, stream>>>(lm_w, wlmt);

    embed_k<<<NTOK * 64 / 256, 256, 0, stream>>>(idx, tokt, post, xb);

    for (int l = 0; l < NLAYER; l++) {
        // ---- attention phase ----
        for (int c = 0; c < nca; c++) {
            const size_t t0 = (size_t)c * chunk_a;
            // qkv = x @ Wqkv
            gemm_bt<0><<<dim3(12, chunk_a / 256), 512, 0, stream>>>(
                xb + t0 * 512, wqkvt + (size_t)l * 786432, qkvc,
                nullptr, nullptr, 512, 512, 1536, 1536);
            // attention, in-place into q-slot of qkvc
            attn_k<<<chunk_a / 4, 256, 0, stream>>>(qkvc);
            // x = attno @ proj_w + proj_b + x   (A = q-slot, lda=1536)
            gemm_bt<1><<<dim3(4, chunk_a / 256), 512, 0, stream>>>(
                qkvc, wprjt + (size_t)l * 262144, xb + t0 * 512,
                proj_b + l * 512, xb + t0 * 512, 512, 1536, 512, 512);
        }
        // x = LN1(x)  (in-place)
        ln_k<<<NTOK / 4, 256, 0, stream>>>(xb, ln1_g + l * 512, ln1_b + l * 512, xb);
        // ---- MLP phase ----
        for (int c = 0; c < ncm; c++) {
            const size_t t0 = (size_t)c * chunk_m;
            // h1 = relu(x @ w1 + b1)
            gemm_bt<2><<<dim3(16, chunk_m / 256), 512, 0, stream>>>(
                xb + t0 * 512, ww1t + (size_t)l * 1048576, h1c,
                b1 + l * 2048, nullptr, 512, 512, 2048, 2048);
            // x = h1 @ w2 + b2 + x   (in-place residual)
            gemm_bt<1><<<dim3(4, chunk_m / 256), 512, 0, stream>>>(
                h1c, ww2t + (size_t)l * 1048576, xb + t0 * 512,
                b2 + l * 512, xb + t0 * 512, 2048, 2048, 512, 512);
        }
        // x = LN2(x)  (in-place)
        ln_k<<<NTOK / 4, 256, 0, stream>>>(xb, ln2_g + l * 512, ln2_b + l * 512, xb);
    }

    // logits = x @ lm_w + lm_b  (N padded to 128, masked fp32 store)
    gemm_bt<3><<<dim3(1, 256), 512, 0, stream>>>(
        xb, wlmt, out, lm_b, nullptr, 512, 512, 128, VOCAB);
}

// Round 6
// 3977.406 us; speedup vs baseline: 1.3218x; 1.0250x over previous
//
#include <hip/hip_runtime.h>
#include <hip/hip_bf16.h>
#include <math.h>

// Problem constants
#define NTOK  65536      // B*T
#define CDIM  512
#define NHEAD 8
#define HSZ   64
#define NLAYER 6
#define DFF   2048
#define VOCAB 65

typedef unsigned short u16;
typedef __attribute__((ext_vector_type(8))) __bf16 bf16x8;
typedef __attribute__((ext_vector_type(4))) float f32x4;
typedef __attribute__((ext_vector_type(8))) unsigned short ushort8;

__device__ __forceinline__ float b2f(u16 u) {
    union { unsigned int i; float f; } x; x.i = ((unsigned int)u) << 16; return x.f;
}
__device__ __forceinline__ u16 f2b(float f) {
    union { float f; unsigned int i; } x; x.f = f;
    unsigned int r = x.i + 0x7fffu + ((x.i >> 16) & 1u);   // RNE
    return (u16)(r >> 16);
}

__device__ __forceinline__ void async16(const u16* g, u16* l) {
    __builtin_amdgcn_global_load_lds(
        (const __attribute__((address_space(1))) void*)g,
        (__attribute__((address_space(3))) void*)l, 16, 0, 0);
}

// ---------------------------------------------------------------------------
// R13 main GEMM: R5 verbatim (best measured: 96us w1-class, 0 bank conflicts,
// 3 blocks/CU, MfmaUtil 29.7). Used for qkv (EPI 0), w1 (EPI 2), head (EPI 3).
// [row][64] LDS + both-sides XOR swizzle (granule^(row&7)), r16/quad reads.
// ---------------------------------------------------------------------------
template<int EPI>
__global__ __launch_bounds__(512)
void gemm_bt(const u16* __restrict__ A, const u16* __restrict__ Bt,
             void* __restrict__ Cout, const float* __restrict__ bias,
             const u16* __restrict__ res, int K, int lda, int N, int Nout)
{
    __shared__ u16 lA[256 * 64];   // 32 KB, [row][64] k-contiguous
    __shared__ u16 lB[128 * 64];   // 16 KB
    const int tid  = threadIdx.x;

    // XCD-aware swizzle
    const int Nx = gridDim.x;
    const int id = blockIdx.y * Nx + blockIdx.x;
    const int xcd = id & 7;
    const int j0  = id >> 3;
    const int mt  = xcd + 8 * (j0 / Nx);
    const int nt  = j0 - (j0 / Nx) * Nx;
    const int m0  = mt * 256;
    const int n0  = nt * 128;

    const int lane = tid & 63;
    const int wv   = tid >> 6;         // 0..7
    const int wr   = (wv >> 1) * 64;   // wave row offset (0,64,128,192)
    const int wc   = (wv & 1) * 64;    // wave col offset (0,64)
    const int r16  = lane & 15;
    const int quad = lane >> 4;
    const int sw8  = r16 & 7;          // read-side swizzle key (= row&7)

    f32x4 acc[4][4] = {};              // acc[j][i], swapped-operand layout

    const int srow = tid >> 3;                         // 0..63
    const int sg   = ((tid & 7) ^ (srow & 7)) * 8;     // pre-swizzled global granule
    const u16* pA  = A  + (size_t)(m0 + srow) * lda + sg;
    const u16* pB  = Bt + (size_t)(n0 + srow) * K + sg;
    u16* lAt = &lA[(size_t)tid * 8];
    u16* lBt = &lB[(size_t)tid * 8];
    const size_t a64 = (size_t)64 * lda, b64 = (size_t)64 * K;

    const int gA0 = ((0 * 4 + quad) ^ sw8) * 8;
    const int gA1 = ((1 * 4 + quad) ^ sw8) * 8;

    for (int k0 = 0; k0 < K; k0 += 64) {
        async16(pA + k0,           lAt);               // A rows   0..63
        async16(pA + a64 + k0,     lAt + 4096);        // A rows  64..127
        async16(pA + 2 * a64 + k0, lAt + 8192);        // A rows 128..191
        async16(pA + 3 * a64 + k0, lAt + 12288);       // A rows 192..255
        async16(pB + k0,           lBt);               // B rows   0..63
        async16(pB + b64 + k0,     lBt + 4096);        // B rows  64..127
        __syncthreads();   // drains vmcnt -> LDS valid

#pragma unroll
        for (int s = 0; s < 2; s++) {
            const int g = s ? gA1 : gA0;
            bf16x8 af[4], bfr[4];
#pragma unroll
            for (int i = 0; i < 4; i++)
                af[i] = *(const bf16x8*)(const void*)&lA[(wr + i * 16 + r16) * 64 + g];
#pragma unroll
            for (int j = 0; j < 4; j++)
                bfr[j] = *(const bf16x8*)(const void*)&lB[(wc + j * 16 + r16) * 64 + g];
#pragma unroll
            for (int j = 0; j < 4; j++)
#pragma unroll
                for (int i = 0; i < 4; i++)
                    acc[j][i] = __builtin_amdgcn_mfma_f32_16x16x32_bf16(bfr[j], af[i], acc[j][i], 0, 0, 0);
        }
        __syncthreads();   // all reads done before next stage overwrites
    }

    // epilogue (swapped layout): row = wr+i*16+r16, cols = wc+j*16+quad*4+r
#pragma unroll
    for (int i = 0; i < 4; i++) {
        const int row = m0 + wr + i * 16 + r16;
#pragma unroll
        for (int j = 0; j < 4; j++) {
            const int colb = n0 + wc + j * 16 + quad * 4;
            float v[4];
#pragma unroll
            for (int r = 0; r < 4; r++) v[r] = acc[j][i][r];
            if (EPI == 1 || EPI == 2) {
                const f32x4 b4 = *(const f32x4*)(const void*)&bias[colb];
#pragma unroll
                for (int r = 0; r < 4; r++) v[r] += b4[r];
            }
            if (EPI == 1) {
                const uint2 rv = *(const uint2*)(const void*)&res[(size_t)row * N + colb];
                v[0] += b2f((u16)(rv.x & 0xffffu));
                v[1] += b2f((u16)(rv.x >> 16));
                v[2] += b2f((u16)(rv.y & 0xffffu));
                v[3] += b2f((u16)(rv.y >> 16));
            }
            if (EPI == 2) {
#pragma unroll
                for (int r = 0; r < 4; r++) v[r] = fmaxf(v[r], 0.f);
            }
            if (EPI == 3) {
#pragma unroll
                for (int r = 0; r < 4; r++) {
                    const int col = colb + r;
                    if (col < Nout)
                        ((float*)Cout)[(size_t)row * Nout + col] = v[r] + bias[col];
                }
            } else {
                uint2 o;
                o.x = (unsigned)f2b(v[0]) | ((unsigned)f2b(v[1]) << 16);
                o.y = (unsigned)f2b(v[2]) | ((unsigned)f2b(v[3]) << 16);
                *(uint2*)(void*)&((u16*)Cout)[(size_t)row * N + colb] = o;
            }
        }
    }
}

// ---------------------------------------------------------------------------
// R13 NEW: gemm_ln — 64x512 full-row tile GEMM with FUSED residual+bias+
// LayerNorm epilogue. Replaces {proj-GEMM + ln1} and {w2-GEMM + ln2}:
//   z = A@Bt^T + bias + res   (f32, unrounded — closer to ref than old
//   bf16-roundtrip through ln_k), then in-block LN over the full 512-wide
//   row: quad shfl_xor reduce -> 8-wave LDS partials -> mu/inv -> write
//   LN(z) as bf16 IN PLACE of xb. Eliminates 12 ln_k dispatches (~400us of
//   HBM round-trip). Tile: 1 block = 64 complete rows; 8 waves each own
//   64 rows x 64 cols (wc = wv*64). Same [row][64]+XOR zero-conflict LDS
//   scheme as gemm_bt (B rows (wc+j*16+r16): row&7 == r16&7 ✓).
//   LDS: A 8KB + B 64KB + red 4.5KB = 76.5KB dynamic -> 2 blocks/CU.
//   Grid = chunk/64 = 512 blocks = exactly one concurrent round (no tail).
//   K order ascending, MFMA pattern identical to gemm_bt.
// ---------------------------------------------------------------------------
__global__ __launch_bounds__(512, 4)
void gemm_ln(const u16* __restrict__ A, const u16* __restrict__ Bt,
             u16* Cout, const float* __restrict__ bias,
             const u16* res, const float* __restrict__ lng,
             const float* __restrict__ lnb, int K, int lda)
{
    extern __shared__ __attribute__((aligned(16))) u16 lds[];
    u16* lA = lds;                          // [64][64]   8 KB
    u16* lB = lds + 4096;                   // [512][64] 64 KB
    float* red  = (float*)(lds + 36864);    // [2][8][64] 4 KB
    float* minv = red + 1024;               // [2][64]  512 B

    const int tid = threadIdx.x;
    const int m0 = blockIdx.x * 64;
    const int lane = tid & 63, wv = tid >> 6;
    const int wc = wv * 64;                 // wave col offset 0..448
    const int r16 = lane & 15, quad = lane >> 4, sw8 = r16 & 7;

    f32x4 acc[4][4] = {};                   // acc[j][i]

    const int srow = tid >> 3;                         // 0..63
    const int sg   = ((tid & 7) ^ (srow & 7)) * 8;
    const u16* pA  = A  + (size_t)(m0 + srow) * lda + sg;
    const u16* pB  = Bt + (size_t)srow * K + sg;
    u16* lAt = &lA[(size_t)tid * 8];
    u16* lBt = &lB[(size_t)tid * 8];
    const size_t b64 = (size_t)64 * K;

    const int gA0 = ((0 * 4 + quad) ^ sw8) * 8;
    const int gA1 = ((1 * 4 + quad) ^ sw8) * 8;

    for (int k0 = 0; k0 < K; k0 += 64) {
        async16(pA + k0, lAt);                         // A rows 0..63
#pragma unroll
        for (int s = 0; s < 8; s++)                    // B rows 0..511
            async16(pB + s * b64 + k0, lBt + s * 4096);
        __syncthreads();

#pragma unroll
        for (int s = 0; s < 2; s++) {
            const int g = s ? gA1 : gA0;
            bf16x8 af[4], bfr[4];
#pragma unroll
            for (int i = 0; i < 4; i++)
                af[i] = *(const bf16x8*)(const void*)&lA[(i * 16 + r16) * 64 + g];
#pragma unroll
            for (int j = 0; j < 4; j++)
                bfr[j] = *(const bf16x8*)(const void*)&lB[(wc + j * 16 + r16) * 64 + g];
#pragma unroll
            for (int j = 0; j < 4; j++)
#pragma unroll
                for (int i = 0; i < 4; i++)
                    acc[j][i] = __builtin_amdgcn_mfma_f32_16x16x32_bf16(bfr[j], af[i], acc[j][i], 0, 0, 0);
        }
        __syncthreads();
    }

    // ---- epilogue: z = acc + bias + res (kept in acc, f32) ----
#pragma unroll
    for (int i = 0; i < 4; i++) {
        const int row = m0 + i * 16 + r16;
#pragma unroll
        for (int j = 0; j < 4; j++) {
            const int colb = wc + j * 16 + quad * 4;
            const f32x4 b4 = *(const f32x4*)(const void*)&bias[colb];
            const uint2 rv = *(const uint2*)(const void*)&res[(size_t)row * 512 + colb];
            acc[j][i][0] += b4[0] + b2f((u16)(rv.x & 0xffffu));
            acc[j][i][1] += b4[1] + b2f((u16)(rv.x >> 16));
            acc[j][i][2] += b4[2] + b2f((u16)(rv.y & 0xffffu));
            acc[j][i][3] += b4[3] + b2f((u16)(rv.y >> 16));
        }
    }

    // ---- row sums: per-lane (16 vals/row) -> quad shfl -> 8-wave LDS ----
    float s1[4], s2[4];
#pragma unroll
    for (int i = 0; i < 4; i++) {
        float a1 = 0.f, a2 = 0.f;
#pragma unroll
        for (int j = 0; j < 4; j++)
#pragma unroll
            for (int r = 0; r < 4; r++) {
                const float v = acc[j][i][r];
                a1 += v; a2 += v * v;
            }
        a1 += __shfl_xor(a1, 16); a1 += __shfl_xor(a1, 32);
        a2 += __shfl_xor(a2, 16); a2 += __shfl_xor(a2, 32);
        s1[i] = a1; s2[i] = a2;
    }
    if (quad == 0) {
#pragma unroll
        for (int i = 0; i < 4; i++) {
            const int rl = i * 16 + r16;
            red[wv * 64 + rl]       = s1[i];
            red[512 + wv * 64 + rl] = s2[i];
        }
    }
    __syncthreads();
    if (tid < 64) {
        float a1 = 0.f, a2 = 0.f;
#pragma unroll
        for (int w = 0; w < 8; w++) {
            a1 += red[w * 64 + tid];
            a2 += red[512 + w * 64 + tid];
        }
        const float mu  = a1 * (1.f / 512.f);
        const float var = a2 * (1.f / 512.f) - mu * mu;
        minv[tid]      = mu;
        minv[64 + tid] = rsqrtf(var + 1e-5f);
    }
    __syncthreads();

    // ---- normalize + write bf16 (in place over xb rows) ----
#pragma unroll
    for (int i = 0; i < 4; i++) {
        const int rl = i * 16 + r16;
        const int row = m0 + rl;
        const float mu = minv[rl], inv = minv[64 + rl];
#pragma unroll
        for (int j = 0; j < 4; j++) {
            const int colb = wc + j * 16 + quad * 4;
            const f32x4 g4 = *(const f32x4*)(const void*)&lng[colb];
            const f32x4 e4 = *(const f32x4*)(const void*)&lnb[colb];
            float v[4];
#pragma unroll
            for (int r = 0; r < 4; r++)
                v[r] = (acc[j][i][r] - mu) * inv * g4[r] + e4[r];
            uint2 o;
            o.x = (unsigned)f2b(v[0]) | ((unsigned)f2b(v[1]) << 16);
            o.y = (unsigned)f2b(v[2]) | ((unsigned)f2b(v[3]) << 16);
            *(uint2*)(void*)&Cout[(size_t)row * 512 + colb] = o;
        }
    }
}

// ---------------------------------------------------------------------------
// Attention: one wave per (b,h). T=8, HS=64. qkv layout [token][q|k|v, h*64+d].
// IN-PLACE into q-slot. NOTE: reference scale = C^-0.5 = 512^-0.5.
// ---------------------------------------------------------------------------
__global__ __launch_bounds__(256)
void attn_k(u16* __restrict__ qkv)
{
    __shared__ float sq[4][8][65], sk[4][8][65], sv[4][8][65], sp[4][64];
    const int w = threadIdx.x >> 6, lane = threadIdx.x & 63;
    const int unit = blockIdx.x * 4 + w;
    const int b = unit >> 3, h = unit & 7;
    const size_t base = (size_t)b * 8 * 1536 + h * 64;
    {
        const int t = lane >> 3, d0 = (lane & 7) * 8;
        const ushort8 q8 = *(const ushort8*)(const void*)&qkv[base + t * 1536 + d0];
        const ushort8 k8 = *(const ushort8*)(const void*)&qkv[base + t * 1536 + 512 + d0];
        const ushort8 v8 = *(const ushort8*)(const void*)&qkv[base + t * 1536 + 1024 + d0];
#pragma unroll
        for (int i = 0; i < 8; i++) {
            sq[w][t][d0 + i] = b2f(q8[i]);
            sk[w][t][d0 + i] = b2f(k8[i]);
            sv[w][t][d0 + i] = b2f(v8[i]);
        }
    }
    __syncthreads();
    const int t = lane >> 3, s = lane & 7;
    float sc = -1e30f;
    if (s <= t) {
        float d = 0.f;
#pragma unroll
        for (int c = 0; c < 64; c++) d += sq[w][t][c] * sk[w][s][c];
        sc = d * 0.04419417382415922f;          // 512^-0.5
    }
    float mx = sc;
#pragma unroll
    for (int m = 1; m < 8; m <<= 1) mx = fmaxf(mx, __shfl_xor(mx, m, 8));
    float e = __expf(sc - mx);
    if (s > t) e = 0.f;
    float sum = e;
#pragma unroll
    for (int m = 1; m < 8; m <<= 1) sum += __shfl_xor(sum, m, 8);
    sp[w][lane] = e / sum;
    __syncthreads();
    {
        const int tt = lane >> 3, d0 = (lane & 7) * 8;
        float a[8] = {};
#pragma unroll
        for (int ss = 0; ss < 8; ss++) {
            const float p = sp[w][tt * 8 + ss];
#pragma unroll
            for (int i = 0; i < 8; i++) a[i] += p * sv[w][ss][d0 + i];
        }
        ushort8 o;
#pragma unroll
        for (int i = 0; i < 8; i++) o[i] = f2b(a[i]);
        *(ushort8*)(void*)&qkv[base + tt * 1536 + d0] = o;   // q-slot
    }
}

// ---------------------------------------------------------------------------
// LayerNorm: kept for reference/unused (fused into gemm_ln).
// ---------------------------------------------------------------------------
__global__ __launch_bounds__(256)
void ln_k(const u16* __restrict__ y, const float* __restrict__ g,
          const float* __restrict__ be, u16* __restrict__ x)
{
    const int w = threadIdx.x >> 6, lane = threadIdx.x & 63;
    const size_t tok = (size_t)blockIdx.x * 4 + w;
    const u16* row = y + tok * 512 + lane * 8;
    ushort8 raw = *(const ushort8*)(const void*)row;
    float v[8];
#pragma unroll
    for (int i = 0; i < 8; i++) v[i] = b2f(raw[i]);
    float s = 0.f;
#pragma unroll
    for (int i = 0; i < 8; i++) s += v[i];
#pragma unroll
    for (int m = 1; m < 64; m <<= 1) s += __shfl_xor(s, m, 64);
    const float mu = s * (1.f / 512.f);
    float q = 0.f;
#pragma unroll
    for (int i = 0; i < 8; i++) { float d = v[i] - mu; q += d * d; }
#pragma unroll
    for (int m = 1; m < 64; m <<= 1) q += __shfl_xor(q, m, 64);
    const float inv = rsqrtf(q * (1.f / 512.f) + 1e-5f);
    f32x4 g0  = *(const f32x4*)(const void*)&g[lane * 8];
    f32x4 g1  = *(const f32x4*)(const void*)&g[lane * 8 + 4];
    f32x4 b0  = *(const f32x4*)(const void*)&be[lane * 8];
    f32x4 b1v = *(const f32x4*)(const void*)&be[lane * 8 + 4];
    ushort8 o;
#pragma unroll
    for (int i = 0; i < 4; i++) o[i]     = f2b((v[i] - mu) * inv * g0[i] + b0[i]);
#pragma unroll
    for (int i = 0; i < 4; i++) o[i + 4] = f2b((v[i + 4] - mu) * inv * g1[i] + b1v[i]);
    *(ushort8*)(void*)&x[tok * 512 + lane * 8] = o;
}

// ---------------------------------------------------------------------------
// Embedding: vectorized. thread -> (token, 8-col segment).
// ---------------------------------------------------------------------------
__global__ __launch_bounds__(256)
void embed_k(const int* __restrict__ idx, const float* __restrict__ tokt,
             const float* __restrict__ pos, u16* __restrict__ xb)
{
    const int gid = blockIdx.x * 256 + threadIdx.x;    // < NTOK*64
    const int tk = gid >> 6, seg = (gid & 63) * 8;
    const int t = tk & 7;
    const int ix = idx[tk];
    const f32x4 a0 = *(const f32x4*)(const void*)&tokt[(size_t)ix * 512 + seg];
    const f32x4 a1 = *(const f32x4*)(const void*)&tokt[(size_t)ix * 512 + seg + 4];
    const f32x4 p0 = *(const f32x4*)(const void*)&pos[t * 512 + seg];
    const f32x4 p1 = *(const f32x4*)(const void*)&pos[t * 512 + seg + 4];
    ushort8 o;
#pragma unroll
    for (int i = 0; i < 4; i++) o[i]     = f2b(a0[i] + p0[i]);
#pragma unroll
    for (int i = 0; i < 4; i++) o[i + 4] = f2b(a1[i] + p1[i]);
    *(ushort8*)(void*)&xb[(size_t)tk * 512 + seg] = o;
}

// ---------------------------------------------------------------------------
// Weight converts (fp32 -> bf16 B^T layouts), LDS-tiled transposes
// ---------------------------------------------------------------------------
__global__ __launch_bounds__(256)
void conv_t2_k(const float* __restrict__ in, u16* __restrict__ out, int K, int N)
{
    __shared__ float t[32][33];
    const int tx = threadIdx.x & 31, ty4 = (threadIdx.x >> 5) * 4;
    const int n0 = blockIdx.x * 32, k0 = blockIdx.y * 32, l = blockIdx.z;
    const size_t per = (size_t)K * N;
    const float* src = in + l * per;
#pragma unroll
    for (int r = 0; r < 4; r++)
        t[ty4 + r][tx] = src[(size_t)(k0 + ty4 + r) * N + n0 + tx];
    __syncthreads();
    u16* dst = out + l * per;
#pragma unroll
    for (int r = 0; r < 4; r++)
        dst[(size_t)(n0 + ty4 + r) * K + k0 + tx] = f2b(t[tx][ty4 + r]);
}

__global__ __launch_bounds__(256)
void conv_qkv2_k(const float* __restrict__ wq, const float* __restrict__ wk,
                 const float* __restrict__ wv, u16* __restrict__ out)
{
    __shared__ float t[32][33];
    const int tx = threadIdx.x & 31, ty4 = (threadIdx.x >> 5) * 4;
    const int c0 = blockIdx.x * 32, d0 = blockIdx.y * 32;
    const int z = blockIdx.z;
    const int sel = z / 48, rem = z - sel * 48;
    const int l = rem >> 3, h = rem & 7;
    const float* src = (sel == 0) ? wq : (sel == 1) ? wk : wv;
    const float* sb = src + (((size_t)l * 8 + h) * 512) * 64;
#pragma unroll
    for (int r = 0; r < 4; r++)
        t[ty4 + r][tx] = sb[(size_t)(c0 + ty4 + r) * 64 + d0 + tx];
    __syncthreads();
    u16* dst = out + (size_t)l * 786432 + (size_t)(sel * 512 + h * 64 + d0) * 512;
#pragma unroll
    for (int r = 0; r < 4; r++)
        dst[(size_t)(ty4 + r) * 512 + c0 + tx] = f2b(t[tx][ty4 + r]);
}

__global__ __launch_bounds__(256)
void conv_lm_k(const float* __restrict__ lm_w, u16* __restrict__ out)
{
    int gid = blockIdx.x * 256 + threadIdx.x;        // < 128*512
    int n = gid >> 9, c = gid & 511;
    out[gid] = (n < VOCAB) ? f2b(lm_w[(size_t)c * VOCAB + n]) : (u16)0;
}

// ---------------------------------------------------------------------------
extern "C" void kernel_launch(void* const* d_in, const int* in_sizes, int n_in,
                              void* d_out, int out_size, void* d_ws, size_t ws_size,
                              hipStream_t stream)
{
    const int*   idx    = (const int*)  d_in[0];
    const float* tokt   = (const float*)d_in[1];
    const float* post   = (const float*)d_in[2];
    const float* wq     = (const float*)d_in[3];
    const float* wk     = (const float*)d_in[4];
    const float* wvp    = (const float*)d_in[5];
    const float* proj_w = (const float*)d_in[6];
    const float* proj_b = (const float*)d_in[7];
    const float* w1     = (const float*)d_in[8];
    const float* b1     = (const float*)d_in[9];
    const float* w2     = (const float*)d_in[10];
    const float* b2     = (const float*)d_in[11];
    const float* ln1_g  = (const float*)d_in[12];
    const float* ln1_b  = (const float*)d_in[13];
    const float* ln2_g  = (const float*)d_in[14];
    const float* ln2_b  = (const float*)d_in[15];
    const float* lm_w   = (const float*)d_in[16];
    const float* lm_b   = (const float*)d_in[17];
    float* out = (float*)d_out;

    // 76.5 KiB dynamic LDS opt-in for gemm_ln (once per process).
    static int smem_set = 0;
    if (!smem_set) {
        smem_set = 1;
        hipFuncSetAttribute(reinterpret_cast<const void*>(&gemm_ln),
                            hipFuncAttributeMaxDynamicSharedMemorySize, 78336);
    }

    char* ws = (char*)d_ws;
    u16* wqkvt = (u16*)(ws + 0);                     //  9,437,184
    u16* wprjt = (u16*)(ws + 9437184);               //  3,145,728
    u16* ww1t  = (u16*)(ws + 12582912);              // 12,582,912
    u16* ww2t  = (u16*)(ws + 25165824);              // 12,582,912
    u16* wlmt  = (u16*)(ws + 37748736);              //    131,072
    u16* xb    = (u16*)(ws + 37879808);              // 67,108,864  residual
    char* big  = ws + 104988672;                     // transient

    const size_t fixed_bytes = 104988672ull;
    const size_t avail = (ws_size > fixed_bytes) ? (ws_size - fixed_bytes) : 0;
    int chunk_a = 8192, chunk_m = 8192;
    const int cands[3] = {65536, 32768, 16384};
    for (int i = 0; i < 3; i++)
        if ((size_t)cands[i] * 3072ull <= avail) { chunk_a = cands[i]; break; }
    for (int i = 0; i < 3; i++)
        if ((size_t)cands[i] * 4096ull <= avail) { chunk_m = cands[i]; break; }
    const int nca = NTOK / chunk_a, ncm = NTOK / chunk_m;
    u16* qkvc = (u16*)big;                           // chunk_a x 1536
    u16* h1c  = (u16*)big;                           // chunk_m x 2048

    conv_qkv2_k<<<dim3(16, 2, 144), 256, 0, stream>>>(wq, wk, wvp, wqkvt);
    conv_t2_k  <<<dim3(16, 16, 6), 256, 0, stream>>>(proj_w, wprjt, 512, 512);
    conv_t2_k  <<<dim3(64, 16, 6), 256, 0, stream>>>(w1, ww1t, 512, 2048);
    conv_t2_k  <<<dim3(16, 64, 6), 256, 0, stream>>>(w2, ww2t, 2048, 512);
    conv_lm_k  <<<128 * 512 / 256, 256, 0, stream>>>(lm_w, wlmt);

    embed_k<<<NTOK * 64 / 256, 256, 0, stream>>>(idx, tokt, post, xb);

    for (int l = 0; l < NLAYER; l++) {
        // ---- attention phase ----
        for (int c = 0; c < nca; c++) {
            const size_t t0 = (size_t)c * chunk_a;
            // qkv = x @ Wqkv
            gemm_bt<0><<<dim3(12, chunk_a / 256), 512, 0, stream>>>(
                xb + t0 * 512, wqkvt + (size_t)l * 786432, qkvc,
                nullptr, nullptr, 512, 512, 1536, 1536);
            // attention, in-place into q-slot of qkvc
            attn_k<<<chunk_a / 4, 256, 0, stream>>>(qkvc);
            // x = LN1(attno @ proj_w + proj_b + x)   — fused GEMM+residual+LN
            gemm_ln<<<dim3(chunk_a / 64), 512, 78336, stream>>>(
                qkvc, wprjt + (size_t)l * 262144, xb + t0 * 512,
                proj_b + l * 512, xb + t0 * 512,
                ln1_g + l * 512, ln1_b + l * 512, 512, 1536);
        }
        // ---- MLP phase ----
        for (int c = 0; c < ncm; c++) {
            const size_t t0 = (size_t)c * chunk_m;
            // h1 = relu(x @ w1 + b1)
            gemm_bt<2><<<dim3(16, chunk_m / 256), 512, 0, stream>>>(
                xb + t0 * 512, ww1t + (size_t)l * 1048576, h1c,
                b1 + l * 2048, nullptr, 512, 512, 2048, 2048);
            // x = LN2(h1 @ w2 + b2 + x)   — fused GEMM+residual+LN
            gemm_ln<<<dim3(chunk_m / 64), 512, 78336, stream>>>(
                h1c, ww2t + (size_t)l * 1048576, xb + t0 * 512,
                b2 + l * 512, xb + t0 * 512,
                ln2_g + l * 512, ln2_b + l * 512, 2048, 2048);
        }
    }

    // logits = x @ lm_w + lm_b  (N padded to 128, masked fp32 store)
    gemm_bt<3><<<dim3(1, 256), 512, 0, stream>>>(
        xb, wlmt, out, lm_b, nullptr, 512, 512, 128, VOCAB);
}